// Round 1
// baseline (455.193 us; speedup 1.0000x reference)
//
#include <hip/hip_runtime.h>
#include <hip/hip_bf16.h>
#include <stdint.h>

#define BB 8
#define SS 4096
#define DD 512
#define HH 8
#define HDIM 64

typedef unsigned short u16;
typedef __attribute__((ext_vector_type(4))) float f32x4;
typedef __attribute__((ext_vector_type(4))) short s16x4;
typedef __attribute__((ext_vector_type(8))) short s16x8;

__device__ __forceinline__ u16 f2bf(float f) {
  uint32_t x = __builtin_bit_cast(uint32_t, f);
  x += 0x7fffu + ((x >> 16) & 1u);
  return (u16)(x >> 16);
}
__device__ __forceinline__ float bf2f(u16 u) {
  uint32_t x = (uint32_t)u << 16;
  return __builtin_bit_cast(float, x);
}

// ---------------- weight conversion: 4 x [512*512] f32 -> bf16 ----------------
__global__ void cvt_weights(const float* __restrict__ w0, const float* __restrict__ w1,
                            const float* __restrict__ w2, const float* __restrict__ w3,
                            u16* __restrict__ out) {
  int i = blockIdx.x * blockDim.x + threadIdx.x;
  const int n = DD * DD;
  if (i < n) {
    out[i]         = f2bf(w0[i]);
    out[n + i]     = f2bf(w1[i]);
    out[2 * n + i] = f2bf(w2[i]);
    out[3 * n + i] = f2bf(w3[i]);
  }
}

// ---------------- mask dtype sniff + unpack to canonical u8 ----------------
// bool may arrive as u8 (numpy bool), i32, or f32. Deterministic sniff:
// int32 0/1 words -> mode 0; bytes all {0,1} -> mode 1; else f32 -> mode 2.
__global__ void mask_unpack(const void* __restrict__ mraw, uint8_t* __restrict__ mk, int n) {
  __shared__ int bad[3];
  __shared__ int mode;
  const int t = threadIdx.x;
  if (t < 3) bad[t] = 0;
  __syncthreads();
  const uint32_t* w = (const uint32_t*)mraw;
  const uint32_t x = w[t];  // first 256 words = 1024 bytes (safe: n>=32768 elements, >=1B each)
  const bool w01 = (x == 0u) || (x == 1u);
  const uint32_t ob = x | (x >> 8) | (x >> 16) | (x >> 24);
  const bool u01 = ((ob & 0xFEu) == 0u);
  if (!w01) atomicAdd(&bad[0], 1);
  if (!u01) atomicAdd(&bad[1], 1);
  __syncthreads();
  if (t == 0) mode = (bad[0] == 0) ? 0 : (bad[1] == 0 ? 1 : 2);
  __syncthreads();
  const int md = mode;
  for (int i = t; i < n; i += 256) {
    uint8_t v;
    if (md == 0)      v = (uint8_t)(w[i] & 1u);
    else if (md == 1) v = ((const uint8_t*)mraw)[i] ? 1 : 0;
    else              v = (w[i] != 0u) ? 1 : 0;  // f32: 0.0f is all-zero bits
    mk[i] = v;
  }
}

// ---------------- GEMM: C[m][n] = sum_k A[m][k] * Bw[n][k] + bias[n] ----------------
// TA in {float, u16(bf16)}; TC in {float, u16(bf16)}. Bw is bf16 [N][K] row-major.
// 128x128 tile, BK=32, 4 waves (2x2), mfma_f32_16x16x32_bf16, reg-staged LDS with
// padded stride LDK=40 (80B rows) to avoid the 16-way bank conflict of linear [128][32].
template <typename TA, typename TC>
__global__ __launch_bounds__(256, 2)
void gemm_bt(const TA* __restrict__ A, const u16* __restrict__ Bw,
             const float* __restrict__ bias, TC* __restrict__ C,
             int M, int N, int K) {
  constexpr int BK = 32, LDK = 40;
  __shared__ u16 sA[128 * LDK];
  __shared__ u16 sB[128 * LDK];

  const int tid = threadIdx.x;
  const int lane = tid & 63, wv = tid >> 6;
  const int wr = (wv >> 1) * 64, wc = (wv & 1) * 64;
  const int r16 = lane & 15, g = lane >> 4;
  const int col0 = blockIdx.x * 128;   // N-tile fastest: 4 consecutive blocks share A tile
  const int row0 = blockIdx.y * 128;

  f32x4 acc[4][4];
#pragma unroll
  for (int a = 0; a < 4; ++a)
#pragma unroll
    for (int b = 0; b < 4; ++b) acc[a][b] = (f32x4){0.f, 0.f, 0.f, 0.f};

  const int nkt = K / BK;
  for (int kt = 0; kt < nkt; ++kt) {
    __syncthreads();
    // stage: each thread 2 chunks of 8 elems for A and for B
#pragma unroll
    for (int it = 0; it < 2; ++it) {
      const int c = tid + it * 256;
      const int row = c >> 2, cc = c & 3;
      {
        const TA* ap = A + (size_t)(row0 + row) * K + kt * BK + cc * 8;
        s16x8 pk;
        if constexpr (sizeof(TA) == 4) {
          const f32x4 a0 = *(const f32x4*)ap;
          const f32x4 a1 = *(const f32x4*)(ap + 4);
          pk = (s16x8){(short)f2bf(a0[0]), (short)f2bf(a0[1]), (short)f2bf(a0[2]), (short)f2bf(a0[3]),
                       (short)f2bf(a1[0]), (short)f2bf(a1[1]), (short)f2bf(a1[2]), (short)f2bf(a1[3])};
        } else {
          pk = *(const s16x8*)ap;
        }
        *(s16x8*)&sA[row * LDK + cc * 8] = pk;
      }
      {
        const u16* bp = Bw + (size_t)(col0 + row) * K + kt * BK + cc * 8;
        *(s16x8*)&sB[row * LDK + cc * 8] = *(const s16x8*)bp;
      }
    }
    __syncthreads();

    // fragment layout (16x16x32 bf16): lane = e + 16*g holds elems 0..3 at k=4g+i,
    // elems 4..7 at k=16+4g+i.
    s16x8 af[4], bq[4];
#pragma unroll
    for (int mf = 0; mf < 4; ++mf) {
      const u16* p = &sA[(wr + mf * 16 + r16) * LDK + g * 4];
      const s16x4 lo = *(const s16x4*)p;
      const s16x4 hi = *(const s16x4*)(p + 16);
      af[mf] = (s16x8){lo[0], lo[1], lo[2], lo[3], hi[0], hi[1], hi[2], hi[3]};
    }
#pragma unroll
    for (int nf = 0; nf < 4; ++nf) {
      const u16* p = &sB[(wc + nf * 16 + r16) * LDK + g * 4];
      const s16x4 lo = *(const s16x4*)p;
      const s16x4 hi = *(const s16x4*)(p + 16);
      bq[nf] = (s16x8){lo[0], lo[1], lo[2], lo[3], hi[0], hi[1], hi[2], hi[3]};
    }
#pragma unroll
    for (int mf = 0; mf < 4; ++mf)
#pragma unroll
      for (int nf = 0; nf < 4; ++nf)
        acc[mf][nf] = __builtin_amdgcn_mfma_f32_16x16x32_bf16(af[mf], bq[nf], acc[mf][nf], 0, 0, 0);
  }

  // epilogue: C/D layout col=lane&15, row=4*(lane>>4)+i
#pragma unroll
  for (int nf = 0; nf < 4; ++nf) {
    const int col = col0 + wc + nf * 16 + r16;
    const float bv = bias[col];
#pragma unroll
    for (int mf = 0; mf < 4; ++mf) {
#pragma unroll
      for (int i = 0; i < 4; ++i) {
        const int row = row0 + wr + mf * 16 + g * 4 + i;
        const float v = acc[mf][nf][i] + bv;
        if constexpr (sizeof(TC) == 4) C[(size_t)row * N + col] = v;
        else                           C[(size_t)row * N + col] = (TC)f2bf(v);
      }
    }
  }
}

// ---------------- banded attention ----------------
// block = (b*H+h, 64-row chunk). K/V staged in LDS permuted: perm(d) = (d&15)*4 + (d>>4)
// so lane (d16,g)'s 4 dims {d16+16j} are one contiguous float4. 16-lane shuffle reduce.
// Score: (OOB || mask[key]) ? MIN_SCORE : q.k  (replace, preserves all-masked uniform case).
// PV: OOB keys excluded via zeroed V; masked in-range keys DO contribute (matches ref).
template <typename TQ>
__global__ __launch_bounds__(256)
void attn_win(const TQ* __restrict__ Qp, const TQ* __restrict__ Kp,
              const TQ* __restrict__ Vp, const uint8_t* __restrict__ mk,
              u16* __restrict__ O) {
  constexpr int KR = 96;  // 64 rows + 2*16 halo
  __shared__ float sK[KR][HDIM];
  __shared__ float sV[KR][HDIM];
  __shared__ float sM[KR];

  const int bh = blockIdx.x;
  const int b = bh >> 3, h = bh & 7;
  const int s0 = blockIdx.y * 64;
  const int tid = threadIdx.x;

  for (int c = tid; c < KR * 16; c += 256) {
    const int row = c >> 4, c4 = c & 15;
    const int gr = s0 - 16 + row;
    float kv[4], vv[4];
    if (gr >= 0 && gr < SS) {
      const size_t base = ((size_t)(b * SS + gr)) * DD + h * HDIM + c4 * 4;
      if constexpr (sizeof(TQ) == 4) {
        const f32x4 kk = *(const f32x4*)(Kp + base);
        const f32x4 vx = *(const f32x4*)(Vp + base);
#pragma unroll
        for (int i = 0; i < 4; ++i) { kv[i] = kk[i]; vv[i] = vx[i]; }
      } else {
        const s16x4 kk = *(const s16x4*)(Kp + base);
        const s16x4 vx = *(const s16x4*)(Vp + base);
#pragma unroll
        for (int i = 0; i < 4; ++i) { kv[i] = bf2f((u16)kk[i]); vv[i] = bf2f((u16)vx[i]); }
      }
    } else {
#pragma unroll
      for (int i = 0; i < 4; ++i) { kv[i] = 0.f; vv[i] = 0.f; }
    }
#pragma unroll
    for (int i = 0; i < 4; ++i) {
      const int d = c4 * 4 + i;
      const int pd = (d & 15) * 4 + (d >> 4);
      sK[row][pd] = kv[i];
      sV[row][pd] = vv[i];
    }
  }
  for (int r = tid; r < KR; r += 256) {
    const int gr = s0 - 16 + r;
    sM[r] = (gr < 0 || gr >= SS || mk[b * SS + gr]) ? 1.f : 0.f;
  }
  __syncthreads();

  const int wv = tid >> 6, lane = tid & 63;
  const int g = lane >> 4, d16 = lane & 15;

  for (int rr = 0; rr < 16; rr += 4) {
    const int lr = wv * 16 + rr + g;  // local row in [0,64), one per 16-lane group
    const int srow = s0 + lr;
    const TQ* qp = Qp + ((size_t)(b * SS + srow)) * DD + h * HDIM;
    float q0, q1, q2, q3;
    if constexpr (sizeof(TQ) == 4) {
      q0 = qp[d16]; q1 = qp[d16 + 16]; q2 = qp[d16 + 32]; q3 = qp[d16 + 48];
    } else {
      q0 = bf2f(qp[d16]); q1 = bf2f(qp[d16 + 16]); q2 = bf2f(qp[d16 + 32]); q3 = bf2f(qp[d16 + 48]);
    }
    float sc[33];
#pragma unroll
    for (int o = 0; o < 33; ++o) {
      const f32x4 kk = *(const f32x4*)&sK[lr + o][d16 * 4];
      float p = q0 * kk[0] + q1 * kk[1] + q2 * kk[2] + q3 * kk[3];
      p += __shfl_xor(p, 1);
      p += __shfl_xor(p, 2);
      p += __shfl_xor(p, 4);
      p += __shfl_xor(p, 8);
      sc[o] = (sM[lr + o] != 0.f) ? -1.0e9f : p;
    }
    float mx = sc[0];
#pragma unroll
    for (int o = 1; o < 33; ++o) mx = fmaxf(mx, sc[o]);
    float sum = 0.f;
#pragma unroll
    for (int o = 0; o < 33; ++o) { const float e = __expf(sc[o] - mx); sc[o] = e; sum += e; }
    const float inv = 1.f / sum;
    f32x4 acc = (f32x4){0.f, 0.f, 0.f, 0.f};
#pragma unroll
    for (int o = 0; o < 33; ++o) {
      const f32x4 vx = *(const f32x4*)&sV[lr + o][d16 * 4];
      acc += (sc[o] * inv) * vx;
    }
    u16* op = O + ((size_t)(b * SS + srow)) * DD + h * HDIM;
    op[d16]      = f2bf(acc[0]);
    op[d16 + 16] = f2bf(acc[1]);
    op[d16 + 32] = f2bf(acc[2]);
    op[d16 + 48] = f2bf(acc[3]);
  }
}

// ---------------- launch ----------------
extern "C" void kernel_launch(void* const* d_in, const int* in_sizes, int n_in,
                              void* d_out, int out_size, void* d_ws, size_t ws_size,
                              hipStream_t stream) {
  const float* query = (const float*)d_in[0];
  const float* key   = (const float*)d_in[1];
  const float* value = (const float*)d_in[2];
  const void*  mraw  = d_in[3];
  const float* Wq = (const float*)d_in[4];
  const float* bq = (const float*)d_in[5];
  const float* Wk = (const float*)d_in[6];
  const float* bk = (const float*)d_in[7];
  const float* Wv = (const float*)d_in[8];
  const float* bv = (const float*)d_in[9];
  const float* Wo = (const float*)d_in[10];
  const float* bo = (const float*)d_in[11];

  const int M = BB * SS, N = DD, K = DD;

  char* ws = (char*)d_ws;
  size_t off = 0;
  auto carve = [&](size_t bytes) -> char* {
    char* p = ws + off;
    off = (off + bytes + 255) & ~(size_t)255;
    return p;
  };
  u16* wAll   = (u16*)carve((size_t)4 * DD * DD * sizeof(u16));
  uint8_t* mk = (uint8_t*)carve((size_t)BB * SS);

  const size_t qkv_f32 = (size_t)M * DD * 4;
  const size_t qkv_b16 = (size_t)M * DD * 2;
  const size_t ao_b    = (size_t)M * DD * 2;
  const bool f32p = (off + 3 * qkv_f32 + ao_b + 1024) <= ws_size;

  cvt_weights<<<(DD * DD + 255) / 256, 256, 0, stream>>>(Wq, Wk, Wv, Wo, wAll);
  mask_unpack<<<1, 256, 0, stream>>>(mraw, mk, BB * SS);

  const dim3 gg(N / 128, M / 128);
  const dim3 ga(BB * HH, SS / 64);
  u16* AO;
  if (f32p) {
    float* Qf = (float*)carve(qkv_f32);
    float* Kf = (float*)carve(qkv_f32);
    float* Vf = (float*)carve(qkv_f32);
    AO = (u16*)carve(ao_b);
    gemm_bt<float, float><<<gg, 256, 0, stream>>>(query, wAll,              bq, Qf, M, N, K);
    gemm_bt<float, float><<<gg, 256, 0, stream>>>(key,   wAll + DD * DD,    bk, Kf, M, N, K);
    gemm_bt<float, float><<<gg, 256, 0, stream>>>(value, wAll + 2 * DD * DD, bv, Vf, M, N, K);
    attn_win<float><<<ga, 256, 0, stream>>>(Qf, Kf, Vf, mk, AO);
  } else {
    u16* Qb = (u16*)carve(qkv_b16);
    u16* Kb = (u16*)carve(qkv_b16);
    u16* Vb = (u16*)carve(qkv_b16);
    AO = (u16*)carve(ao_b);
    gemm_bt<float, u16><<<gg, 256, 0, stream>>>(query, wAll,              bq, Qb, M, N, K);
    gemm_bt<float, u16><<<gg, 256, 0, stream>>>(key,   wAll + DD * DD,    bk, Kb, M, N, K);
    gemm_bt<float, u16><<<gg, 256, 0, stream>>>(value, wAll + 2 * DD * DD, bv, Vb, M, N, K);
    attn_win<u16><<<ga, 256, 0, stream>>>(Qb, Kb, Vb, mk, AO);
  }
  gemm_bt<u16, float><<<gg, 256, 0, stream>>>(AO, wAll + 3 * DD * DD, bo, (float*)d_out, M, N, K);
}

// Round 2
// 355.743 us; speedup vs baseline: 1.2796x; 1.2796x over previous
//
#include <hip/hip_runtime.h>
#include <hip/hip_bf16.h>
#include <stdint.h>

#define BB 8
#define SS 4096
#define DD 512
#define HH 8
#define HDIM 64

typedef unsigned short u16;
typedef __attribute__((ext_vector_type(4))) float f32x4;
typedef __attribute__((ext_vector_type(4))) short s16x4;
typedef __attribute__((ext_vector_type(8))) short s16x8;

__device__ __forceinline__ u16 f2bf(float f) {
  uint32_t x = __builtin_bit_cast(uint32_t, f);
  x += 0x7fffu + ((x >> 16) & 1u);
  return (u16)(x >> 16);
}
__device__ __forceinline__ float bf2f(u16 u) {
  uint32_t x = (uint32_t)u << 16;
  return __builtin_bit_cast(float, x);
}

// ---------------- weight conversion: 4 x [512*512] f32 -> bf16 ----------------
__global__ void cvt_weights(const float* __restrict__ w0, const float* __restrict__ w1,
                            const float* __restrict__ w2, const float* __restrict__ w3,
                            u16* __restrict__ out) {
  int i = blockIdx.x * blockDim.x + threadIdx.x;
  const int n = DD * DD;
  if (i < n) {
    out[i]         = f2bf(w0[i]);
    out[n + i]     = f2bf(w1[i]);
    out[2 * n + i] = f2bf(w2[i]);
    out[3 * n + i] = f2bf(w3[i]);
  }
}

// ---------------- mask dtype sniff + unpack to canonical u8 ----------------
__global__ void mask_unpack(const void* __restrict__ mraw, uint8_t* __restrict__ mk, int n) {
  __shared__ int bad[3];
  __shared__ int mode;
  const int t = threadIdx.x;
  if (t < 3) bad[t] = 0;
  __syncthreads();
  const uint32_t* w = (const uint32_t*)mraw;
  const uint32_t x = w[t];
  const bool w01 = (x == 0u) || (x == 1u);
  const uint32_t ob = x | (x >> 8) | (x >> 16) | (x >> 24);
  const bool u01 = ((ob & 0xFEu) == 0u);
  if (!w01) atomicAdd(&bad[0], 1);
  if (!u01) atomicAdd(&bad[1], 1);
  __syncthreads();
  if (t == 0) mode = (bad[0] == 0) ? 0 : (bad[1] == 0 ? 1 : 2);
  __syncthreads();
  const int md = mode;
  for (int i = t; i < n; i += 256) {
    uint8_t v;
    if (md == 0)      v = (uint8_t)(w[i] & 1u);
    else if (md == 1) v = ((const uint8_t*)mraw)[i] ? 1 : 0;
    else              v = (w[i] != 0u) ? 1 : 0;
    mk[i] = v;
  }
}

// ---------------- GEMM: C[m][n] = sum_k A[m][k] * Bw[n][k] + bias[n] ----------------
template <typename TA, typename TC>
__global__ __launch_bounds__(256, 2)
void gemm_bt(const TA* __restrict__ A, const u16* __restrict__ Bw,
             const float* __restrict__ bias, TC* __restrict__ C,
             int M, int N, int K) {
  constexpr int BK = 32, LDK = 40;
  __shared__ u16 sA[128 * LDK];
  __shared__ u16 sB[128 * LDK];

  const int tid = threadIdx.x;
  const int lane = tid & 63, wv = tid >> 6;
  const int wr = (wv >> 1) * 64, wc = (wv & 1) * 64;
  const int r16 = lane & 15, g = lane >> 4;
  const int col0 = blockIdx.x * 128;
  const int row0 = blockIdx.y * 128;

  f32x4 acc[4][4];
#pragma unroll
  for (int a = 0; a < 4; ++a)
#pragma unroll
    for (int b = 0; b < 4; ++b) acc[a][b] = (f32x4){0.f, 0.f, 0.f, 0.f};

  const int nkt = K / BK;
  for (int kt = 0; kt < nkt; ++kt) {
    __syncthreads();
#pragma unroll
    for (int it = 0; it < 2; ++it) {
      const int c = tid + it * 256;
      const int row = c >> 2, cc = c & 3;
      {
        const TA* ap = A + (size_t)(row0 + row) * K + kt * BK + cc * 8;
        s16x8 pk;
        if constexpr (sizeof(TA) == 4) {
          const f32x4 a0 = *(const f32x4*)ap;
          const f32x4 a1 = *(const f32x4*)(ap + 4);
          pk = (s16x8){(short)f2bf(a0[0]), (short)f2bf(a0[1]), (short)f2bf(a0[2]), (short)f2bf(a0[3]),
                       (short)f2bf(a1[0]), (short)f2bf(a1[1]), (short)f2bf(a1[2]), (short)f2bf(a1[3])};
        } else {
          pk = *(const s16x8*)ap;
        }
        *(s16x8*)&sA[row * LDK + cc * 8] = pk;
      }
      {
        const u16* bp = Bw + (size_t)(col0 + row) * K + kt * BK + cc * 8;
        *(s16x8*)&sB[row * LDK + cc * 8] = *(const s16x8*)bp;
      }
    }
    __syncthreads();

    s16x8 af[4], bq[4];
#pragma unroll
    for (int mf = 0; mf < 4; ++mf) {
      const u16* p = &sA[(wr + mf * 16 + r16) * LDK + g * 4];
      const s16x4 lo = *(const s16x4*)p;
      const s16x4 hi = *(const s16x4*)(p + 16);
      af[mf] = (s16x8){lo[0], lo[1], lo[2], lo[3], hi[0], hi[1], hi[2], hi[3]};
    }
#pragma unroll
    for (int nf = 0; nf < 4; ++nf) {
      const u16* p = &sB[(wc + nf * 16 + r16) * LDK + g * 4];
      const s16x4 lo = *(const s16x4*)p;
      const s16x4 hi = *(const s16x4*)(p + 16);
      bq[nf] = (s16x8){lo[0], lo[1], lo[2], lo[3], hi[0], hi[1], hi[2], hi[3]};
    }
#pragma unroll
    for (int mf = 0; mf < 4; ++mf)
#pragma unroll
      for (int nf = 0; nf < 4; ++nf)
        acc[mf][nf] = __builtin_amdgcn_mfma_f32_16x16x32_bf16(af[mf], bq[nf], acc[mf][nf], 0, 0, 0);
  }

#pragma unroll
  for (int nf = 0; nf < 4; ++nf) {
    const int col = col0 + wc + nf * 16 + r16;
    const float bv = bias[col];
#pragma unroll
    for (int mf = 0; mf < 4; ++mf) {
#pragma unroll
      for (int i = 0; i < 4; ++i) {
        const int row = row0 + wr + mf * 16 + g * 4 + i;
        const float v = acc[mf][nf][i] + bv;
        if constexpr (sizeof(TC) == 4) C[(size_t)row * N + col] = v;
        else                           C[(size_t)row * N + col] = (TC)f2bf(v);
      }
    }
  }
}

// ---------------- MFMA banded attention (f32 Q/K/V, hi/lo split precision) -------------
// Per block: (b,h) x 64-row chunk. Swapped QK^T: S^T = K·Q^T so each lane holds one
// q-row's 24 scores (x4 lane-groups = 96 keys) lane-local; softmax = per-lane reduce +
// shfl_xor(16,32). Exp'd S^T acc IS the PV B-operand fragment (out^T = V^T·P^T) — no
// LDS round-trip. hi/lo bf16 split on Q,K,P,V (drop lo·lo) keeps ~f32 score precision.
// Bias: off-band -2e9, in-band masked/OOB -1e9 (matches ref all-masked uniform case);
// OOB rows have V zeroed so pads drop out of PV like the reference.
__device__ __forceinline__ void hilo8(const f32x4& a0, const f32x4& a1, s16x8& h, s16x8& l) {
#pragma unroll
  for (int j = 0; j < 4; ++j) {
    const float f = a0[j];
    const u16 hb = f2bf(f);
    h[j] = (short)hb;
    l[j] = (short)f2bf(f - bf2f(hb));
  }
#pragma unroll
  for (int j = 0; j < 4; ++j) {
    const float f = a1[j];
    const u16 hb = f2bf(f);
    h[4 + j] = (short)hb;
    l[4 + j] = (short)f2bf(f - bf2f(hb));
  }
}

__global__ __launch_bounds__(256, 3)
void attn_mfma(const float* __restrict__ Qp, const float* __restrict__ Kp,
               const float* __restrict__ Vp, const uint8_t* __restrict__ mk,
               u16* __restrict__ O) {
  constexpr int KR = 96, LDF = 68;  // pad 64->68 floats: balanced banks for b128/b32 reads
  __shared__ float sK[KR * LDF];
  __shared__ float sV[KR * LDF];
  __shared__ float sM[KR];

  const int bh = blockIdx.x;
  const int b = bh >> 3, h = bh & 7;
  const int s0 = blockIdx.y * 64;
  const int tid = threadIdx.x;

  // stage K,V (f32, zero OOB) + mask
  for (int c = tid; c < KR * 16; c += 256) {
    const int row = c >> 4, c4 = c & 15;
    const int gr = s0 - 16 + row;
    f32x4 kk = (f32x4){0.f, 0.f, 0.f, 0.f}, vv = (f32x4){0.f, 0.f, 0.f, 0.f};
    if (gr >= 0 && gr < SS) {
      const size_t base = ((size_t)(b * SS + gr)) * DD + h * HDIM + c4 * 4;
      kk = *(const f32x4*)(Kp + base);
      vv = *(const f32x4*)(Vp + base);
    }
    *(f32x4*)&sK[row * LDF + c4 * 4] = kk;
    *(f32x4*)&sV[row * LDF + c4 * 4] = vv;
  }
  for (int r = tid; r < KR; r += 256) {
    const int gr = s0 - 16 + r;
    sM[r] = (gr < 0 || gr >= SS || mk[b * SS + gr]) ? 1.f : 0.f;
  }
  __syncthreads();

  const int wv = tid >> 6, lane = tid & 63;
  const int c = lane & 15, g = lane >> 4;   // c: q-row (B/D col) or A-row; g: k-group
  const int qloc = wv * 16 + c;
  const int qrow = s0 + qloc;

  // Q fragments (B operand of S^T): lane c+16g holds Q[c][4g+i], Q[c][16+4g+i] per kstep
  const float* qp = Qp + ((size_t)(b * SS + qrow)) * DD + h * HDIM;
  s16x8 qh[2], qlo[2];
#pragma unroll
  for (int ks = 0; ks < 2; ++ks) {
    const f32x4 a0 = *(const f32x4*)(qp + 32 * ks + 4 * g);
    const f32x4 a1 = *(const f32x4*)(qp + 32 * ks + 16 + 4 * g);
    hilo8(a0, a1, qh[ks], qlo[ks]);
  }

  // S^T = K·Q^T over 6 key-tiles
  f32x4 st[6];
#pragma unroll
  for (int kt = 0; kt < 6; ++kt) st[kt] = (f32x4){0.f, 0.f, 0.f, 0.f};
#pragma unroll
  for (int kt = 0; kt < 6; ++kt) {
    const float* kp = &sK[(kt * 16 + c) * LDF];
    s16x8 kh[2], kl[2];
#pragma unroll
    for (int ks = 0; ks < 2; ++ks) {
      const f32x4 k0 = *(const f32x4*)(kp + 32 * ks + 4 * g);
      const f32x4 k1 = *(const f32x4*)(kp + 32 * ks + 16 + 4 * g);
      hilo8(k0, k1, kh[ks], kl[ks]);
    }
    st[kt] = __builtin_amdgcn_mfma_f32_16x16x32_bf16(kh[0], qh[0], st[kt], 0, 0, 0);
    st[kt] = __builtin_amdgcn_mfma_f32_16x16x32_bf16(kh[1], qh[1], st[kt], 0, 0, 0);
    st[kt] = __builtin_amdgcn_mfma_f32_16x16x32_bf16(kh[0], qlo[0], st[kt], 0, 0, 0);
    st[kt] = __builtin_amdgcn_mfma_f32_16x16x32_bf16(kh[1], qlo[1], st[kt], 0, 0, 0);
    st[kt] = __builtin_amdgcn_mfma_f32_16x16x32_bf16(kl[0], qh[0], st[kt], 0, 0, 0);
    st[kt] = __builtin_amdgcn_mfma_f32_16x16x32_bf16(kl[1], qh[1], st[kt], 0, 0, 0);
  }

  // bias (replace semantics) + online softmax, all lane-local per q-row
  float mx = -3.0e9f;
#pragma unroll
  for (int kt = 0; kt < 6; ++kt) {
#pragma unroll
    for (int i = 0; i < 4; ++i) {
      const int kl_ = kt * 16 + 4 * g + i;
      const int delta = kl_ - 16 - qloc;
      float v;
      if (delta < -16 || delta > 16) v = -2.0e9f;
      else if (sM[kl_] != 0.f)       v = -1.0e9f;
      else                           v = st[kt][i];
      st[kt][i] = v;
      mx = fmaxf(mx, v);
    }
  }
  mx = fmaxf(mx, __shfl_xor(mx, 16));
  mx = fmaxf(mx, __shfl_xor(mx, 32));
  float sum = 0.f;
#pragma unroll
  for (int kt = 0; kt < 6; ++kt) {
#pragma unroll
    for (int i = 0; i < 4; ++i) {
      const float e = __expf(st[kt][i] - mx);
      st[kt][i] = e;
      sum += e;
    }
  }
  sum += __shfl_xor(sum, 16);
  sum += __shfl_xor(sum, 32);
  const float inv = 1.f / sum;

  // P^T fragments (B operand of PV): lane c+16g: keys {32ks+4g+i} from st[2ks],
  // keys {32ks+16+4g+i} from st[2ks+1]. hi/lo split.
  s16x8 ph[3], pl[3];
#pragma unroll
  for (int ks = 0; ks < 3; ++ks) {
#pragma unroll
    for (int i = 0; i < 4; ++i) {
      const float e0 = st[2 * ks][i];
      const u16 h0 = f2bf(e0);
      ph[ks][i] = (short)h0;
      pl[ks][i] = (short)f2bf(e0 - bf2f(h0));
      const float e1 = st[2 * ks + 1][i];
      const u16 h1 = f2bf(e1);
      ph[ks][4 + i] = (short)h1;
      pl[ks][4 + i] = (short)f2bf(e1 - bf2f(h1));
    }
  }

  // out^T = V^T · P^T : 4 dim-tiles x 3 ksteps. V^T A-frag via 8 scalar LDS reads
  // (bank-balanced with LDF=68), hi/lo split.
  f32x4 ot[4];
#pragma unroll
  for (int dt = 0; dt < 4; ++dt) ot[dt] = (f32x4){0.f, 0.f, 0.f, 0.f};
#pragma unroll
  for (int dt = 0; dt < 4; ++dt) {
#pragma unroll
    for (int ks = 0; ks < 3; ++ks) {
      f32x4 v0, v1;
#pragma unroll
      for (int i = 0; i < 4; ++i) v0[i] = sV[(32 * ks + 4 * g + i) * LDF + dt * 16 + c];
#pragma unroll
      for (int i = 0; i < 4; ++i) v1[i] = sV[(32 * ks + 16 + 4 * g + i) * LDF + dt * 16 + c];
      s16x8 vh, vl;
      hilo8(v0, v1, vh, vl);
      ot[dt] = __builtin_amdgcn_mfma_f32_16x16x32_bf16(vh, ph[ks], ot[dt], 0, 0, 0);
      ot[dt] = __builtin_amdgcn_mfma_f32_16x16x32_bf16(vh, pl[ks], ot[dt], 0, 0, 0);
      ot[dt] = __builtin_amdgcn_mfma_f32_16x16x32_bf16(vl, ph[ks], ot[dt], 0, 0, 0);
    }
  }

  // store: lane holds out^T col=qrow, rows = dims dt*16 + 4g + i (4 consecutive u16)
  u16* op = O + ((size_t)(b * SS + qrow)) * DD + h * HDIM;
#pragma unroll
  for (int dt = 0; dt < 4; ++dt) {
    s16x4 pk;
#pragma unroll
    for (int i = 0; i < 4; ++i) pk[i] = (short)f2bf(ot[dt][i] * inv);
    *(s16x4*)&op[dt * 16 + 4 * g] = pk;
  }
}

// ---------------- legacy VALU attention (bf16 fallback path only) ----------------
template <typename TQ>
__global__ __launch_bounds__(256)
void attn_win(const TQ* __restrict__ Qp, const TQ* __restrict__ Kp,
              const TQ* __restrict__ Vp, const uint8_t* __restrict__ mk,
              u16* __restrict__ O) {
  constexpr int KR = 96;
  __shared__ float sK[KR][HDIM];
  __shared__ float sV[KR][HDIM];
  __shared__ float sM[KR];

  const int bh = blockIdx.x;
  const int b = bh >> 3, h = bh & 7;
  const int s0 = blockIdx.y * 64;
  const int tid = threadIdx.x;

  for (int c = tid; c < KR * 16; c += 256) {
    const int row = c >> 4, c4 = c & 15;
    const int gr = s0 - 16 + row;
    float kv[4], vv[4];
    if (gr >= 0 && gr < SS) {
      const size_t base = ((size_t)(b * SS + gr)) * DD + h * HDIM + c4 * 4;
      const s16x4 kk = *(const s16x4*)(Kp + base);
      const s16x4 vx = *(const s16x4*)(Vp + base);
#pragma unroll
      for (int i = 0; i < 4; ++i) { kv[i] = bf2f((u16)kk[i]); vv[i] = bf2f((u16)vx[i]); }
    } else {
#pragma unroll
      for (int i = 0; i < 4; ++i) { kv[i] = 0.f; vv[i] = 0.f; }
    }
#pragma unroll
    for (int i = 0; i < 4; ++i) {
      const int d = c4 * 4 + i;
      const int pd = (d & 15) * 4 + (d >> 4);
      sK[row][pd] = kv[i];
      sV[row][pd] = vv[i];
    }
  }
  for (int r = tid; r < KR; r += 256) {
    const int gr = s0 - 16 + r;
    sM[r] = (gr < 0 || gr >= SS || mk[b * SS + gr]) ? 1.f : 0.f;
  }
  __syncthreads();

  const int wv = tid >> 6, lane = tid & 63;
  const int g = lane >> 4, d16 = lane & 15;

  for (int rr = 0; rr < 16; rr += 4) {
    const int lr = wv * 16 + rr + g;
    const int srow = s0 + lr;
    const TQ* qp = Qp + ((size_t)(b * SS + srow)) * DD + h * HDIM;
    float q0 = bf2f(qp[d16]), q1 = bf2f(qp[d16 + 16]), q2 = bf2f(qp[d16 + 32]), q3 = bf2f(qp[d16 + 48]);
    float sc[33];
#pragma unroll
    for (int o = 0; o < 33; ++o) {
      const f32x4 kk = *(const f32x4*)&sK[lr + o][d16 * 4];
      float p = q0 * kk[0] + q1 * kk[1] + q2 * kk[2] + q3 * kk[3];
      p += __shfl_xor(p, 1);
      p += __shfl_xor(p, 2);
      p += __shfl_xor(p, 4);
      p += __shfl_xor(p, 8);
      sc[o] = (sM[lr + o] != 0.f) ? -1.0e9f : p;
    }
    float mx = sc[0];
#pragma unroll
    for (int o = 1; o < 33; ++o) mx = fmaxf(mx, sc[o]);
    float sum = 0.f;
#pragma unroll
    for (int o = 0; o < 33; ++o) { const float e = __expf(sc[o] - mx); sc[o] = e; sum += e; }
    const float inv = 1.f / sum;
    f32x4 acc = (f32x4){0.f, 0.f, 0.f, 0.f};
#pragma unroll
    for (int o = 0; o < 33; ++o) {
      const f32x4 vx = *(const f32x4*)&sV[lr + o][d16 * 4];
      acc += (sc[o] * inv) * vx;
    }
    u16* op = O + ((size_t)(b * SS + srow)) * DD + h * HDIM;
    op[d16]      = f2bf(acc[0]);
    op[d16 + 16] = f2bf(acc[1]);
    op[d16 + 32] = f2bf(acc[2]);
    op[d16 + 48] = f2bf(acc[3]);
  }
}

// ---------------- launch ----------------
extern "C" void kernel_launch(void* const* d_in, const int* in_sizes, int n_in,
                              void* d_out, int out_size, void* d_ws, size_t ws_size,
                              hipStream_t stream) {
  const float* query = (const float*)d_in[0];
  const float* key   = (const float*)d_in[1];
  const float* value = (const float*)d_in[2];
  const void*  mraw  = d_in[3];
  const float* Wq = (const float*)d_in[4];
  const float* bq = (const float*)d_in[5];
  const float* Wk = (const float*)d_in[6];
  const float* bk = (const float*)d_in[7];
  const float* Wv = (const float*)d_in[8];
  const float* bv = (const float*)d_in[9];
  const float* Wo = (const float*)d_in[10];
  const float* bo = (const float*)d_in[11];

  const int M = BB * SS, N = DD, K = DD;

  char* ws = (char*)d_ws;
  size_t off = 0;
  auto carve = [&](size_t bytes) -> char* {
    char* p = ws + off;
    off = (off + bytes + 255) & ~(size_t)255;
    return p;
  };
  u16* wAll   = (u16*)carve((size_t)4 * DD * DD * sizeof(u16));
  uint8_t* mk = (uint8_t*)carve((size_t)BB * SS);

  const size_t qkv_f32 = (size_t)M * DD * 4;
  const size_t qkv_b16 = (size_t)M * DD * 2;
  const size_t ao_b    = (size_t)M * DD * 2;
  const bool f32p = (off + 3 * qkv_f32 + ao_b + 1024) <= ws_size;

  cvt_weights<<<(DD * DD + 255) / 256, 256, 0, stream>>>(Wq, Wk, Wv, Wo, wAll);
  mask_unpack<<<1, 256, 0, stream>>>(mraw, mk, BB * SS);

  const dim3 gg(N / 128, M / 128);
  const dim3 ga(BB * HH, SS / 64);
  u16* AO;
  if (f32p) {
    float* Qf = (float*)carve(qkv_f32);
    float* Kf = (float*)carve(qkv_f32);
    float* Vf = (float*)carve(qkv_f32);
    AO = (u16*)carve(ao_b);
    gemm_bt<float, float><<<gg, 256, 0, stream>>>(query, wAll,               bq, Qf, M, N, K);
    gemm_bt<float, float><<<gg, 256, 0, stream>>>(key,   wAll + DD * DD,     bk, Kf, M, N, K);
    gemm_bt<float, float><<<gg, 256, 0, stream>>>(value, wAll + 2 * DD * DD, bv, Vf, M, N, K);
    attn_mfma<<<ga, 256, 0, stream>>>(Qf, Kf, Vf, mk, AO);
  } else {
    u16* Qb = (u16*)carve(qkv_b16);
    u16* Kb = (u16*)carve(qkv_b16);
    u16* Vb = (u16*)carve(qkv_b16);
    AO = (u16*)carve(ao_b);
    gemm_bt<float, u16><<<gg, 256, 0, stream>>>(query, wAll,               bq, Qb, M, N, K);
    gemm_bt<float, u16><<<gg, 256, 0, stream>>>(key,   wAll + DD * DD,     bk, Kb, M, N, K);
    gemm_bt<float, u16><<<gg, 256, 0, stream>>>(value, wAll + 2 * DD * DD, bv, Vb, M, N, K);
    attn_win<u16><<<ga, 256, 0, stream>>>(Qb, Kb, Vb, mk, AO);
  }
  gemm_bt<u16, float><<<gg, 256, 0, stream>>>(AO, wAll + 3 * DD * DD, bo, (float*)d_out, M, N, K);
}

// Round 3
// 315.283 us; speedup vs baseline: 1.4438x; 1.1283x over previous
//
#include <hip/hip_runtime.h>
#include <hip/hip_bf16.h>
#include <stdint.h>

#define BB 8
#define SS 4096
#define DD 512
#define HH 8
#define HDIM 64

typedef unsigned short u16;
typedef __attribute__((ext_vector_type(4))) float f32x4;
typedef __attribute__((ext_vector_type(4))) short s16x4;
typedef __attribute__((ext_vector_type(8))) short s16x8;

__device__ __forceinline__ u16 f2bf(float f) {
  uint32_t x = __builtin_bit_cast(uint32_t, f);
  x += 0x7fffu + ((x >> 16) & 1u);
  return (u16)(x >> 16);
}
__device__ __forceinline__ float bf2f(u16 u) {
  uint32_t x = (uint32_t)u << 16;
  return __builtin_bit_cast(float, x);
}

// ---------------- weight conversion: 4 x [512*512] f32 -> bf16 ----------------
__global__ void cvt_weights(const float* __restrict__ w0, const float* __restrict__ w1,
                            const float* __restrict__ w2, const float* __restrict__ w3,
                            u16* __restrict__ out) {
  int i = blockIdx.x * blockDim.x + threadIdx.x;
  const int n = DD * DD;
  if (i < n) {
    out[i]         = f2bf(w0[i]);
    out[n + i]     = f2bf(w1[i]);
    out[2 * n + i] = f2bf(w2[i]);
    out[3 * n + i] = f2bf(w3[i]);
  }
}

// ---------------- mask dtype sniff + unpack to canonical u8 ----------------
__global__ void mask_unpack(const void* __restrict__ mraw, uint8_t* __restrict__ mk, int n) {
  __shared__ int bad[3];
  __shared__ int mode;
  const int t = threadIdx.x;
  if (t < 3) bad[t] = 0;
  __syncthreads();
  const uint32_t* w = (const uint32_t*)mraw;
  const uint32_t x = w[t];
  const bool w01 = (x == 0u) || (x == 1u);
  const uint32_t ob = x | (x >> 8) | (x >> 16) | (x >> 24);
  const bool u01 = ((ob & 0xFEu) == 0u);
  if (!w01) atomicAdd(&bad[0], 1);
  if (!u01) atomicAdd(&bad[1], 1);
  __syncthreads();
  if (t == 0) mode = (bad[0] == 0) ? 0 : (bad[1] == 0 ? 1 : 2);
  __syncthreads();
  const int md = mode;
  for (int i = t; i < n; i += 256) {
    uint8_t v;
    if (md == 0)      v = (uint8_t)(w[i] & 1u);
    else if (md == 1) v = ((const uint8_t*)mraw)[i] ? 1 : 0;
    else              v = (w[i] != 0u) ? 1 : 0;
    mk[i] = v;
  }
}

// ---------------- GEMM: C[m][n] = sum_k A[m][k] * Bw[n][k] + bias[n] ----------------
// 1-D swizzled grid: the 4 col-blocks sharing an A row-panel get linear ids
// {j, j+8, j+16, j+24} -> same XCD (id%8) and same dispatch epoch -> A panel is
// fetched into that XCD's L2 once and shared. N is fixed at 512 (4 col-blocks).
template <typename TA, typename TC>
__global__ __launch_bounds__(256, 2)
void gemm_bt(const TA* __restrict__ A, const u16* __restrict__ Bw,
             const float* __restrict__ bias, TC* __restrict__ C,
             int M, int N, int K) {
  constexpr int BK = 32, LDK = 40;
  __shared__ u16 sA[128 * LDK];
  __shared__ u16 sB[128 * LDK];

  const int tid = threadIdx.x;
  const int lane = tid & 63, wv = tid >> 6;
  const int wr = (wv >> 1) * 64, wc = (wv & 1) * 64;
  const int r16 = lane & 15, g = lane >> 4;
  const int lid = blockIdx.x;
  const int rb = (lid >> 5) * 8 + (lid & 7);   // row-block 0..M/128-1
  const int cb = (lid >> 3) & 3;               // col-block 0..3
  const int col0 = cb * 128;
  const int row0 = rb * 128;

  f32x4 acc[4][4];
#pragma unroll
  for (int a = 0; a < 4; ++a)
#pragma unroll
    for (int b = 0; b < 4; ++b) acc[a][b] = (f32x4){0.f, 0.f, 0.f, 0.f};

  const int nkt = K / BK;
  for (int kt = 0; kt < nkt; ++kt) {
    __syncthreads();
#pragma unroll
    for (int it = 0; it < 2; ++it) {
      const int c = tid + it * 256;
      const int row = c >> 2, cc = c & 3;
      {
        const TA* ap = A + (size_t)(row0 + row) * K + kt * BK + cc * 8;
        s16x8 pk;
        if constexpr (sizeof(TA) == 4) {
          const f32x4 a0 = *(const f32x4*)ap;
          const f32x4 a1 = *(const f32x4*)(ap + 4);
          pk = (s16x8){(short)f2bf(a0[0]), (short)f2bf(a0[1]), (short)f2bf(a0[2]), (short)f2bf(a0[3]),
                       (short)f2bf(a1[0]), (short)f2bf(a1[1]), (short)f2bf(a1[2]), (short)f2bf(a1[3])};
        } else {
          pk = *(const s16x8*)ap;
        }
        *(s16x8*)&sA[row * LDK + cc * 8] = pk;
      }
      {
        const u16* bp = Bw + (size_t)(col0 + row) * K + kt * BK + cc * 8;
        *(s16x8*)&sB[row * LDK + cc * 8] = *(const s16x8*)bp;
      }
    }
    __syncthreads();

    s16x8 af[4], bq[4];
#pragma unroll
    for (int mf = 0; mf < 4; ++mf) {
      const u16* p = &sA[(wr + mf * 16 + r16) * LDK + g * 4];
      const s16x4 lo = *(const s16x4*)p;
      const s16x4 hi = *(const s16x4*)(p + 16);
      af[mf] = (s16x8){lo[0], lo[1], lo[2], lo[3], hi[0], hi[1], hi[2], hi[3]};
    }
#pragma unroll
    for (int nf = 0; nf < 4; ++nf) {
      const u16* p = &sB[(wc + nf * 16 + r16) * LDK + g * 4];
      const s16x4 lo = *(const s16x4*)p;
      const s16x4 hi = *(const s16x4*)(p + 16);
      bq[nf] = (s16x8){lo[0], lo[1], lo[2], lo[3], hi[0], hi[1], hi[2], hi[3]};
    }
#pragma unroll
    for (int mf = 0; mf < 4; ++mf)
#pragma unroll
      for (int nf = 0; nf < 4; ++nf)
        acc[mf][nf] = __builtin_amdgcn_mfma_f32_16x16x32_bf16(af[mf], bq[nf], acc[mf][nf], 0, 0, 0);
  }

#pragma unroll
  for (int nf = 0; nf < 4; ++nf) {
    const int col = col0 + wc + nf * 16 + r16;
    const float bv = bias[col];
#pragma unroll
    for (int mf = 0; mf < 4; ++mf) {
#pragma unroll
      for (int i = 0; i < 4; ++i) {
        const int row = row0 + wr + mf * 16 + g * 4 + i;
        const float v = acc[mf][nf][i] + bv;
        if constexpr (sizeof(TC) == 4) C[(size_t)row * N + col] = v;
        else                           C[(size_t)row * N + col] = (TC)f2bf(v);
      }
    }
  }
}

// ---------------- MFMA banded attention v3: LDS-staged bf16 fragments ----------------
// K staged once as fragment-ordered hi+lo bf16 planes (granule (ks,g) holds dims
// {32ks+4g+i, 32ks+16+4g+i} -> A-frag = 1 ds_read_b128, zero per-lane conversion).
// V staged transposed sVT[dim][key-granule] (hi only: V-lo's contribution is below the
// bf16 AO-store rounding). P packed hi-only for same reason. Q/K keep hi+lo (scores
// need ~f32). Swapped QK^T (S^T=K*Q^T) keeps softmax lane-local; exp'd S^T fragments
// ARE the PV B-operand. Bias: off-band -2e9, in-band masked/OOB -1e9 (replace
// semantics -> all-masked row matches ref uniform 1/33; OOB V=0 kills pad terms).
__device__ __forceinline__ void hilo8(const f32x4& a0, const f32x4& a1, s16x8& h, s16x8& l) {
#pragma unroll
  for (int j = 0; j < 4; ++j) {
    const float f = a0[j];
    const u16 hb = f2bf(f);
    h[j] = (short)hb;
    l[j] = (short)f2bf(f - bf2f(hb));
  }
#pragma unroll
  for (int j = 0; j < 4; ++j) {
    const float f = a1[j];
    const u16 hb = f2bf(f);
    h[4 + j] = (short)hb;
    l[4 + j] = (short)f2bf(f - bf2f(hb));
  }
}

__global__ __launch_bounds__(256, 3)
void attn_mfma(const float* __restrict__ Qp, const float* __restrict__ Kp,
               const float* __restrict__ Vp, const uint8_t* __restrict__ mk,
               u16* __restrict__ O) {
  // strides (u16): sKh=72 (144B rows, 16B-aligned, 2-way banks on b128),
  // sKl=68 (b64 reads), sVT=104 (208B rows, 16B-aligned, 2-way banks).
  __shared__ u16 sKh[96 * 72];
  __shared__ u16 sKl[96 * 68];
  __shared__ u16 sVT[64 * 104];
  __shared__ float sM[96];

  const int bh = blockIdx.x;
  const int b = bh >> 3, h = bh & 7;
  const int s0 = blockIdx.y * 64;
  const int tid = threadIdx.x;

  // ---- K staging: 96 rows x 8 granules; granule j=(ks*4+g2) <- dims {32ks+4g2+i, +16} ----
#pragma unroll
  for (int it = 0; it < 3; ++it) {
    const int item = tid + it * 256;
    const int row = item >> 3, j = item & 7;
    const int ks = j >> 2, g2 = j & 3;
    const int gr = s0 - 16 + row;
    f32x4 a0 = (f32x4){0.f, 0.f, 0.f, 0.f}, a1 = (f32x4){0.f, 0.f, 0.f, 0.f};
    if (gr >= 0 && gr < SS) {
      const float* kp = Kp + ((size_t)(b * SS + gr)) * DD + h * HDIM + ks * 32 + g2 * 4;
      a0 = *(const f32x4*)kp;
      a1 = *(const f32x4*)(kp + 16);
    }
    s16x8 hh, ll;
    hilo8(a0, a1, hh, ll);
    *(s16x8*)&sKh[row * 72 + j * 8] = hh;
    *(s16x4*)&sKl[row * 68 + j * 8]     = (s16x4){ll[0], ll[1], ll[2], ll[3]};
    *(s16x4*)&sKl[row * 68 + j * 8 + 4] = (s16x4){ll[4], ll[5], ll[6], ll[7]};
  }
  // ---- V staging (transposed, hi only): key k -> column pos in dim-rows ----
#pragma unroll
  for (int it = 0; it < 6; ++it) {
    const int item = tid + it * 256;
    const int k = item >> 4, dg = item & 15;
    const int gr = s0 - 16 + k;
    f32x4 vv = (f32x4){0.f, 0.f, 0.f, 0.f};
    if (gr >= 0 && gr < SS)
      vv = *(const f32x4*)(Vp + ((size_t)(b * SS + gr)) * DD + h * HDIM + dg * 4);
    const int ks = k >> 5, rem = k & 31, hf = rem >> 4, q = rem & 15;
    const int g2 = q >> 2, i2 = q & 3;
    const int pos = (ks * 4 + g2) * 8 + hf * 4 + i2;
#pragma unroll
    for (int i = 0; i < 4; ++i) sVT[(dg * 4 + i) * 104 + pos] = f2bf(vv[i]);
  }
  for (int r = tid; r < 96; r += 256) {
    const int gr = s0 - 16 + r;
    sM[r] = (gr < 0 || gr >= SS || mk[b * SS + gr]) ? 1.f : 0.f;
  }
  __syncthreads();

  const int wv = tid >> 6, lane = tid & 63;
  const int c = lane & 15, g = lane >> 4;
  const int qloc = wv * 16 + c;
  const int qrow = s0 + qloc;

  // Q fragments (B operand of S^T), hi+lo from global f32
  const float* qp = Qp + ((size_t)(b * SS + qrow)) * DD + h * HDIM;
  s16x8 qh[2], qlo[2];
#pragma unroll
  for (int ks = 0; ks < 2; ++ks) {
    const f32x4 a0 = *(const f32x4*)(qp + 32 * ks + 4 * g);
    const f32x4 a1 = *(const f32x4*)(qp + 32 * ks + 16 + 4 * g);
    hilo8(a0, a1, qh[ks], qlo[ks]);
  }

  // S^T = K·Q^T over 6 key-tiles: frags straight from LDS, 6 MFMA/tile
  f32x4 st[6];
#pragma unroll
  for (int kt = 0; kt < 6; ++kt) st[kt] = (f32x4){0.f, 0.f, 0.f, 0.f};
#pragma unroll
  for (int kt = 0; kt < 6; ++kt) {
    const int rb72 = (kt * 16 + c) * 72;
    const int rb68 = (kt * 16 + c) * 68;
#pragma unroll
    for (int ks = 0; ks < 2; ++ks) {
      const s16x8 kh = *(const s16x8*)&sKh[rb72 + ks * 32 + g * 8];
      const s16x4 l0 = *(const s16x4*)&sKl[rb68 + ks * 32 + g * 8];
      const s16x4 l1 = *(const s16x4*)&sKl[rb68 + ks * 32 + g * 8 + 4];
      const s16x8 kl = (s16x8){l0[0], l0[1], l0[2], l0[3], l1[0], l1[1], l1[2], l1[3]};
      st[kt] = __builtin_amdgcn_mfma_f32_16x16x32_bf16(kh, qh[ks], st[kt], 0, 0, 0);
      st[kt] = __builtin_amdgcn_mfma_f32_16x16x32_bf16(kh, qlo[ks], st[kt], 0, 0, 0);
      st[kt] = __builtin_amdgcn_mfma_f32_16x16x32_bf16(kl, qh[ks], st[kt], 0, 0, 0);
    }
  }

  // bias (replace) + softmax, lane-local per q-row
  float mx = -3.0e9f;
#pragma unroll
  for (int kt = 0; kt < 6; ++kt) {
#pragma unroll
    for (int i = 0; i < 4; ++i) {
      const int kl_ = kt * 16 + 4 * g + i;
      const int delta = kl_ - 16 - qloc;
      float v;
      if (delta < -16 || delta > 16) v = -2.0e9f;
      else if (sM[kl_] != 0.f)       v = -1.0e9f;
      else                           v = st[kt][i];
      st[kt][i] = v;
      mx = fmaxf(mx, v);
    }
  }
  mx = fmaxf(mx, __shfl_xor(mx, 16));
  mx = fmaxf(mx, __shfl_xor(mx, 32));
  float sum = 0.f;
#pragma unroll
  for (int kt = 0; kt < 6; ++kt) {
#pragma unroll
    for (int i = 0; i < 4; ++i) {
      const float e = __expf(st[kt][i] - mx);
      st[kt][i] = e;
      sum += e;
    }
  }
  sum += __shfl_xor(sum, 16);
  sum += __shfl_xor(sum, 32);
  const float inv = 1.f / sum;

  // P^T fragments (B operand of PV), hi only
  s16x8 ph[3];
#pragma unroll
  for (int ks = 0; ks < 3; ++ks) {
#pragma unroll
    for (int i = 0; i < 4; ++i) {
      ph[ks][i]     = (short)f2bf(st[2 * ks][i]);
      ph[ks][4 + i] = (short)f2bf(st[2 * ks + 1][i]);
    }
  }

  // out^T = V^T·P^T : 4 dim-tiles x 3 ksteps, A-frag = 1 b128 from sVT
  f32x4 ot[4];
#pragma unroll
  for (int dt = 0; dt < 4; ++dt) ot[dt] = (f32x4){0.f, 0.f, 0.f, 0.f};
#pragma unroll
  for (int dt = 0; dt < 4; ++dt) {
    const int rbv = (dt * 16 + c) * 104;
#pragma unroll
    for (int ks = 0; ks < 3; ++ks) {
      const s16x8 vh = *(const s16x8*)&sVT[rbv + ks * 32 + g * 8];
      ot[dt] = __builtin_amdgcn_mfma_f32_16x16x32_bf16(vh, ph[ks], ot[dt], 0, 0, 0);
    }
  }

  u16* op = O + ((size_t)(b * SS + qrow)) * DD + h * HDIM;
#pragma unroll
  for (int dt = 0; dt < 4; ++dt) {
    s16x4 pk;
#pragma unroll
    for (int i = 0; i < 4; ++i) pk[i] = (short)f2bf(ot[dt][i] * inv);
    *(s16x4*)&op[dt * 16 + 4 * g] = pk;
  }
}

// ---------------- legacy VALU attention (bf16 fallback path only) ----------------
template <typename TQ>
__global__ __launch_bounds__(256)
void attn_win(const TQ* __restrict__ Qp, const TQ* __restrict__ Kp,
              const TQ* __restrict__ Vp, const uint8_t* __restrict__ mk,
              u16* __restrict__ O) {
  constexpr int KR = 96;
  __shared__ float sK[KR][HDIM];
  __shared__ float sV[KR][HDIM];
  __shared__ float sM[KR];

  const int bh = blockIdx.x;
  const int b = bh >> 3, h = bh & 7;
  const int s0 = blockIdx.y * 64;
  const int tid = threadIdx.x;

  for (int c = tid; c < KR * 16; c += 256) {
    const int row = c >> 4, c4 = c & 15;
    const int gr = s0 - 16 + row;
    float kv[4], vv[4];
    if (gr >= 0 && gr < SS) {
      const size_t base = ((size_t)(b * SS + gr)) * DD + h * HDIM + c4 * 4;
      const s16x4 kk = *(const s16x4*)(Kp + base);
      const s16x4 vx = *(const s16x4*)(Vp + base);
#pragma unroll
      for (int i = 0; i < 4; ++i) { kv[i] = bf2f((u16)kk[i]); vv[i] = bf2f((u16)vx[i]); }
    } else {
#pragma unroll
      for (int i = 0; i < 4; ++i) { kv[i] = 0.f; vv[i] = 0.f; }
    }
#pragma unroll
    for (int i = 0; i < 4; ++i) {
      const int d = c4 * 4 + i;
      const int pd = (d & 15) * 4 + (d >> 4);
      sK[row][pd] = kv[i];
      sV[row][pd] = vv[i];
    }
  }
  for (int r = tid; r < KR; r += 256) {
    const int gr = s0 - 16 + r;
    sM[r] = (gr < 0 || gr >= SS || mk[b * SS + gr]) ? 1.f : 0.f;
  }
  __syncthreads();

  const int wv = tid >> 6, lane = tid & 63;
  const int g = lane >> 4, d16 = lane & 15;

  for (int rr = 0; rr < 16; rr += 4) {
    const int lr = wv * 16 + rr + g;
    const int srow = s0 + lr;
    const TQ* qp = Qp + ((size_t)(b * SS + srow)) * DD + h * HDIM;
    float q0 = bf2f(qp[d16]), q1 = bf2f(qp[d16 + 16]), q2 = bf2f(qp[d16 + 32]), q3 = bf2f(qp[d16 + 48]);
    float sc[33];
#pragma unroll
    for (int o = 0; o < 33; ++o) {
      const f32x4 kk = *(const f32x4*)&sK[lr + o][d16 * 4];
      float p = q0 * kk[0] + q1 * kk[1] + q2 * kk[2] + q3 * kk[3];
      p += __shfl_xor(p, 1);
      p += __shfl_xor(p, 2);
      p += __shfl_xor(p, 4);
      p += __shfl_xor(p, 8);
      sc[o] = (sM[lr + o] != 0.f) ? -1.0e9f : p;
    }
    float mx = sc[0];
#pragma unroll
    for (int o = 1; o < 33; ++o) mx = fmaxf(mx, sc[o]);
    float sum = 0.f;
#pragma unroll
    for (int o = 0; o < 33; ++o) { const float e = __expf(sc[o] - mx); sc[o] = e; sum += e; }
    const float inv = 1.f / sum;
    f32x4 acc = (f32x4){0.f, 0.f, 0.f, 0.f};
#pragma unroll
    for (int o = 0; o < 33; ++o) {
      const f32x4 vx = *(const f32x4*)&sV[lr + o][d16 * 4];
      acc += (sc[o] * inv) * vx;
    }
    u16* op = O + ((size_t)(b * SS + srow)) * DD + h * HDIM;
    op[d16]      = f2bf(acc[0]);
    op[d16 + 16] = f2bf(acc[1]);
    op[d16 + 32] = f2bf(acc[2]);
    op[d16 + 48] = f2bf(acc[3]);
  }
}

// ---------------- launch ----------------
extern "C" void kernel_launch(void* const* d_in, const int* in_sizes, int n_in,
                              void* d_out, int out_size, void* d_ws, size_t ws_size,
                              hipStream_t stream) {
  const float* query = (const float*)d_in[0];
  const float* key   = (const float*)d_in[1];
  const float* value = (const float*)d_in[2];
  const void*  mraw  = d_in[3];
  const float* Wq = (const float*)d_in[4];
  const float* bq = (const float*)d_in[5];
  const float* Wk = (const float*)d_in[6];
  const float* bk = (const float*)d_in[7];
  const float* Wv = (const float*)d_in[8];
  const float* bv = (const float*)d_in[9];
  const float* Wo = (const float*)d_in[10];
  const float* bo = (const float*)d_in[11];

  const int M = BB * SS, N = DD, K = DD;

  char* ws = (char*)d_ws;
  size_t off = 0;
  auto carve = [&](size_t bytes) -> char* {
    char* p = ws + off;
    off = (off + bytes + 255) & ~(size_t)255;
    return p;
  };
  u16* wAll   = (u16*)carve((size_t)4 * DD * DD * sizeof(u16));
  uint8_t* mk = (uint8_t*)carve((size_t)BB * SS);

  const size_t qkv_f32 = (size_t)M * DD * 4;
  const size_t qkv_b16 = (size_t)M * DD * 2;
  const size_t ao_b    = (size_t)M * DD * 2;
  const bool f32p = (off + 3 * qkv_f32 + ao_b + 1024) <= ws_size;

  cvt_weights<<<(DD * DD + 255) / 256, 256, 0, stream>>>(Wq, Wk, Wv, Wo, wAll);
  mask_unpack<<<1, 256, 0, stream>>>(mraw, mk, BB * SS);

  const dim3 gg((M / 128) * (N / 128));   // 1024, XCD-swizzled in-kernel
  const dim3 ga(BB * HH, SS / 64);
  u16* AO;
  if (f32p) {
    float* Qf = (float*)carve(qkv_f32);
    float* Kf = (float*)carve(qkv_f32);
    float* Vf = (float*)carve(qkv_f32);
    AO = (u16*)carve(ao_b);
    gemm_bt<float, float><<<gg, 256, 0, stream>>>(query, wAll,               bq, Qf, M, N, K);
    gemm_bt<float, float><<<gg, 256, 0, stream>>>(key,   wAll + DD * DD,     bk, Kf, M, N, K);
    gemm_bt<float, float><<<gg, 256, 0, stream>>>(value, wAll + 2 * DD * DD, bv, Vf, M, N, K);
    attn_mfma<<<ga, 256, 0, stream>>>(Qf, Kf, Vf, mk, AO);
  } else {
    u16* Qb = (u16*)carve(qkv_b16);
    u16* Kb = (u16*)carve(qkv_b16);
    u16* Vb = (u16*)carve(qkv_b16);
    AO = (u16*)carve(ao_b);
    gemm_bt<float, u16><<<gg, 256, 0, stream>>>(query, wAll,               bq, Qb, M, N, K);
    gemm_bt<float, u16><<<gg, 256, 0, stream>>>(key,   wAll + DD * DD,     bk, Kb, M, N, K);
    gemm_bt<float, u16><<<gg, 256, 0, stream>>>(value, wAll + 2 * DD * DD, bv, Vb, M, N, K);
    attn_win<u16><<<ga, 256, 0, stream>>>(Qb, Kb, Vb, mk, AO);
  }
  gemm_bt<u16, float><<<gg, 256, 0, stream>>>(AO, wAll + 3 * DD * DD, bo, (float*)d_out, M, N, K);
}

// Round 4
// 258.069 us; speedup vs baseline: 1.7638x; 1.2217x over previous
//
#include <hip/hip_runtime.h>
#include <hip/hip_bf16.h>
#include <stdint.h>

#define BB 8
#define SS 4096
#define DD 512
#define HH 8
#define HDIM 64

typedef unsigned short u16;
typedef __attribute__((ext_vector_type(4))) float f32x4;
typedef __attribute__((ext_vector_type(4))) short s16x4;
typedef __attribute__((ext_vector_type(8))) short s16x8;

__device__ __forceinline__ u16 f2bf(float f) {
  uint32_t x = __builtin_bit_cast(uint32_t, f);
  x += 0x7fffu + ((x >> 16) & 1u);
  return (u16)(x >> 16);
}
__device__ __forceinline__ float bf2f(u16 u) {
  uint32_t x = (uint32_t)u << 16;
  return __builtin_bit_cast(float, x);
}

// async global->LDS, 16B per lane: LDS dest is wave-uniform base + lane*16,
// global src is per-lane.
__device__ __forceinline__ void gld_lds16(const u16* g, u16* l) {
  __builtin_amdgcn_global_load_lds((const __attribute__((address_space(1))) void*)g,
                                   (__attribute__((address_space(3))) void*)l, 16, 0, 0);
}

// ---------------- f32 -> bf16 bulk conversion (32 B/thread/iter) ----------------
__global__ void cvt_f32_bf16(const float* __restrict__ in, u16* __restrict__ out, int n8) {
  int i = blockIdx.x * blockDim.x + threadIdx.x;
  const int stride = gridDim.x * blockDim.x;
  for (; i < n8; i += stride) {
    const f32x4 a0 = *(const f32x4*)(in + (size_t)i * 8);
    const f32x4 a1 = *(const f32x4*)(in + (size_t)i * 8 + 4);
    s16x8 pk;
#pragma unroll
    for (int j = 0; j < 4; ++j) pk[j] = (short)f2bf(a0[j]);
#pragma unroll
    for (int j = 0; j < 4; ++j) pk[4 + j] = (short)f2bf(a1[j]);
    *(s16x8*)(out + (size_t)i * 8) = pk;
  }
}

// ---------------- weight conversion: 4 x [512*512] f32 -> bf16 ----------------
__global__ void cvt_weights(const float* __restrict__ w0, const float* __restrict__ w1,
                            const float* __restrict__ w2, const float* __restrict__ w3,
                            u16* __restrict__ out) {
  int i = blockIdx.x * blockDim.x + threadIdx.x;
  const int n = DD * DD;
  if (i < n) {
    out[i]         = f2bf(w0[i]);
    out[n + i]     = f2bf(w1[i]);
    out[2 * n + i] = f2bf(w2[i]);
    out[3 * n + i] = f2bf(w3[i]);
  }
}

// ---------------- mask dtype sniff + unpack to canonical u8 ----------------
__global__ void mask_unpack(const void* __restrict__ mraw, uint8_t* __restrict__ mk, int n) {
  __shared__ int bad[3];
  __shared__ int mode;
  const int t = threadIdx.x;
  if (t < 3) bad[t] = 0;
  __syncthreads();
  const uint32_t* w = (const uint32_t*)mraw;
  const uint32_t x = w[t];
  const bool w01 = (x == 0u) || (x == 1u);
  const uint32_t ob = x | (x >> 8) | (x >> 16) | (x >> 24);
  const bool u01 = ((ob & 0xFEu) == 0u);
  if (!w01) atomicAdd(&bad[0], 1);
  if (!u01) atomicAdd(&bad[1], 1);
  __syncthreads();
  if (t == 0) mode = (bad[0] == 0) ? 0 : (bad[1] == 0 ? 1 : 2);
  __syncthreads();
  const int md = mode;
  for (int i = blockIdx.x * 256 + t; i < n; i += gridDim.x * 256) {
    uint8_t v;
    if (md == 0)      v = (uint8_t)(w[i] & 1u);
    else if (md == 1) v = ((const uint8_t*)mraw)[i] ? 1 : 0;
    else              v = (w[i] != 0u) ? 1 : 0;
    mk[i] = v;
  }
}

// ---------------- GEMM m97-structure: C[m][n] = sum_k A[m][k]*Bw[n][k] + bias[n] ----
// A, Bw bf16 [.][K] row-major. 128x128 tile, BK=32, 4 waves 2x2, LDS linear [128][32],
// staging = global_load_lds dwordx4 (4 issues/thread/K-step), fragment = single
// ds_read_b128 at cols 8g..8g+7. A and B share the same k-column permutation, and
// MFMA sums over all 32 k-columns -> result is permutation-invariant (exact).
// Grid 1-D: 4 col-siblings of one A row-panel land on the same XCD (id%8).
template <typename TC>
__global__ __launch_bounds__(256, 2)
void gemm97(const u16* __restrict__ A, const u16* __restrict__ Bw,
            const float* __restrict__ bias, TC* __restrict__ C,
            int M, int N, int K) {
  __shared__ u16 sA[128 * 32];
  __shared__ u16 sB[128 * 32];

  const int tid = threadIdx.x;
  const int lane = tid & 63, wv = tid >> 6;
  const int wr = (wv >> 1) * 64, wc = (wv & 1) * 64;
  const int c = lane & 15, g = lane >> 4;
  const int lid = blockIdx.x;
  const int rb = (lid >> 5) * 8 + (lid & 7);
  const int cb = (lid >> 3) & 3;
  const int col0 = cb * 128, row0 = rb * 128;

  // staging: thread t covers (row=t/4, col-chunk=t%4) and the +64-row twin
  const int srow = tid >> 2, scol = (tid & 3) * 8;
  const u16* a_src = A + (size_t)(row0 + srow) * K + scol;
  const u16* b_src = Bw + (size_t)(col0 + srow) * K + scol;
  u16* sa0 = &sA[wv * 512];
  u16* sa1 = &sA[2048 + wv * 512];
  u16* sb0 = &sB[wv * 512];
  u16* sb1 = &sB[2048 + wv * 512];

  f32x4 acc[4][4];
#pragma unroll
  for (int a = 0; a < 4; ++a)
#pragma unroll
    for (int b = 0; b < 4; ++b) acc[a][b] = (f32x4){0.f, 0.f, 0.f, 0.f};

  const int nkt = K / 32;
  for (int kt = 0; kt < nkt; ++kt) {
    __syncthreads();
    const int ko = kt * 32;
    gld_lds16(a_src + ko, sa0);
    gld_lds16(a_src + (size_t)64 * K + ko, sa1);
    gld_lds16(b_src + ko, sb0);
    gld_lds16(b_src + (size_t)64 * K + ko, sb1);
    __syncthreads();   // drains vmcnt -> LDS tile complete

    s16x8 af[4], bq[4];
#pragma unroll
    for (int mf = 0; mf < 4; ++mf) af[mf] = *(const s16x8*)&sA[(wr + mf * 16 + c) * 32 + g * 8];
#pragma unroll
    for (int nf = 0; nf < 4; ++nf) bq[nf] = *(const s16x8*)&sB[(wc + nf * 16 + c) * 32 + g * 8];
#pragma unroll
    for (int mf = 0; mf < 4; ++mf)
#pragma unroll
      for (int nf = 0; nf < 4; ++nf)
        acc[mf][nf] = __builtin_amdgcn_mfma_f32_16x16x32_bf16(af[mf], bq[nf], acc[mf][nf], 0, 0, 0);
  }

  // epilogue: C/D layout col=lane&15, row=4*(lane>>4)+i
#pragma unroll
  for (int nf = 0; nf < 4; ++nf) {
    const int col = col0 + wc + nf * 16 + c;
    const float bv = bias[col];
#pragma unroll
    for (int mf = 0; mf < 4; ++mf) {
#pragma unroll
      for (int i = 0; i < 4; ++i) {
        const int row = row0 + wr + mf * 16 + g * 4 + i;
        const float v = acc[mf][nf][i] + bv;
        if constexpr (sizeof(TC) == 4) C[(size_t)row * N + col] = v;
        else                           C[(size_t)row * N + col] = (TC)f2bf(v);
      }
    }
  }
}

// ---------------- MFMA banded attention v3: LDS-staged bf16 fragments ----------------
__device__ __forceinline__ void hilo8(const f32x4& a0, const f32x4& a1, s16x8& h, s16x8& l) {
#pragma unroll
  for (int j = 0; j < 4; ++j) {
    const float f = a0[j];
    const u16 hb = f2bf(f);
    h[j] = (short)hb;
    l[j] = (short)f2bf(f - bf2f(hb));
  }
#pragma unroll
  for (int j = 0; j < 4; ++j) {
    const float f = a1[j];
    const u16 hb = f2bf(f);
    h[4 + j] = (short)hb;
    l[4 + j] = (short)f2bf(f - bf2f(hb));
  }
}

__global__ __launch_bounds__(256, 4)
void attn_mfma(const float* __restrict__ Qp, const float* __restrict__ Kp,
               const float* __restrict__ Vp, const uint8_t* __restrict__ mk,
               u16* __restrict__ O) {
  __shared__ u16 sKh[96 * 72];
  __shared__ u16 sKl[96 * 68];
  __shared__ u16 sVT[64 * 104];
  __shared__ float sM[96];

  const int bh = blockIdx.x;
  const int b = bh >> 3, h = bh & 7;
  const int s0 = blockIdx.y * 64;
  const int tid = threadIdx.x;

#pragma unroll
  for (int it = 0; it < 3; ++it) {
    const int item = tid + it * 256;
    const int row = item >> 3, j = item & 7;
    const int ks = j >> 2, g2 = j & 3;
    const int gr = s0 - 16 + row;
    f32x4 a0 = (f32x4){0.f, 0.f, 0.f, 0.f}, a1 = (f32x4){0.f, 0.f, 0.f, 0.f};
    if (gr >= 0 && gr < SS) {
      const float* kp = Kp + ((size_t)(b * SS + gr)) * DD + h * HDIM + ks * 32 + g2 * 4;
      a0 = *(const f32x4*)kp;
      a1 = *(const f32x4*)(kp + 16);
    }
    s16x8 hh, ll;
    hilo8(a0, a1, hh, ll);
    *(s16x8*)&sKh[row * 72 + j * 8] = hh;
    *(s16x4*)&sKl[row * 68 + j * 8]     = (s16x4){ll[0], ll[1], ll[2], ll[3]};
    *(s16x4*)&sKl[row * 68 + j * 8 + 4] = (s16x4){ll[4], ll[5], ll[6], ll[7]};
  }
#pragma unroll
  for (int it = 0; it < 6; ++it) {
    const int item = tid + it * 256;
    const int k = item >> 4, dg = item & 15;
    const int gr = s0 - 16 + k;
    f32x4 vv = (f32x4){0.f, 0.f, 0.f, 0.f};
    if (gr >= 0 && gr < SS)
      vv = *(const f32x4*)(Vp + ((size_t)(b * SS + gr)) * DD + h * HDIM + dg * 4);
    const int ks = k >> 5, rem = k & 31, hf = rem >> 4, q = rem & 15;
    const int g2 = q >> 2, i2 = q & 3;
    const int pos = (ks * 4 + g2) * 8 + hf * 4 + i2;
#pragma unroll
    for (int i = 0; i < 4; ++i) sVT[(dg * 4 + i) * 104 + pos] = f2bf(vv[i]);
  }
  for (int r = tid; r < 96; r += 256) {
    const int gr = s0 - 16 + r;
    sM[r] = (gr < 0 || gr >= SS || mk[b * SS + gr]) ? 1.f : 0.f;
  }
  __syncthreads();

  const int wv = tid >> 6, lane = tid & 63;
  const int c = lane & 15, g = lane >> 4;
  const int qloc = wv * 16 + c;
  const int qrow = s0 + qloc;

  const float* qp = Qp + ((size_t)(b * SS + qrow)) * DD + h * HDIM;
  s16x8 qh[2], qlo[2];
#pragma unroll
  for (int ks = 0; ks < 2; ++ks) {
    const f32x4 a0 = *(const f32x4*)(qp + 32 * ks + 4 * g);
    const f32x4 a1 = *(const f32x4*)(qp + 32 * ks + 16 + 4 * g);
    hilo8(a0, a1, qh[ks], qlo[ks]);
  }

  f32x4 st[6];
#pragma unroll
  for (int kt = 0; kt < 6; ++kt) st[kt] = (f32x4){0.f, 0.f, 0.f, 0.f};
#pragma unroll
  for (int kt = 0; kt < 6; ++kt) {
    const int rb72 = (kt * 16 + c) * 72;
    const int rb68 = (kt * 16 + c) * 68;
#pragma unroll
    for (int ks = 0; ks < 2; ++ks) {
      const s16x8 kh = *(const s16x8*)&sKh[rb72 + ks * 32 + g * 8];
      const s16x4 l0 = *(const s16x4*)&sKl[rb68 + ks * 32 + g * 8];
      const s16x4 l1 = *(const s16x4*)&sKl[rb68 + ks * 32 + g * 8 + 4];
      const s16x8 kl = (s16x8){l0[0], l0[1], l0[2], l0[3], l1[0], l1[1], l1[2], l1[3]};
      st[kt] = __builtin_amdgcn_mfma_f32_16x16x32_bf16(kh, qh[ks], st[kt], 0, 0, 0);
      st[kt] = __builtin_amdgcn_mfma_f32_16x16x32_bf16(kh, qlo[ks], st[kt], 0, 0, 0);
      st[kt] = __builtin_amdgcn_mfma_f32_16x16x32_bf16(kl, qh[ks], st[kt], 0, 0, 0);
    }
  }

  float mx = -3.0e9f;
#pragma unroll
  for (int kt = 0; kt < 6; ++kt) {
#pragma unroll
    for (int i = 0; i < 4; ++i) {
      const int kl_ = kt * 16 + 4 * g + i;
      const int delta = kl_ - 16 - qloc;
      float v;
      if (delta < -16 || delta > 16) v = -2.0e9f;
      else if (sM[kl_] != 0.f)       v = -1.0e9f;
      else                           v = st[kt][i];
      st[kt][i] = v;
      mx = fmaxf(mx, v);
    }
  }
  mx = fmaxf(mx, __shfl_xor(mx, 16));
  mx = fmaxf(mx, __shfl_xor(mx, 32));
  float sum = 0.f;
#pragma unroll
  for (int kt = 0; kt < 6; ++kt) {
#pragma unroll
    for (int i = 0; i < 4; ++i) {
      const float e = __expf(st[kt][i] - mx);
      st[kt][i] = e;
      sum += e;
    }
  }
  sum += __shfl_xor(sum, 16);
  sum += __shfl_xor(sum, 32);
  const float inv = 1.f / sum;

  s16x8 ph[3];
#pragma unroll
  for (int ks = 0; ks < 3; ++ks) {
#pragma unroll
    for (int i = 0; i < 4; ++i) {
      ph[ks][i]     = (short)f2bf(st[2 * ks][i]);
      ph[ks][4 + i] = (short)f2bf(st[2 * ks + 1][i]);
    }
  }

  f32x4 ot[4];
#pragma unroll
  for (int dt = 0; dt < 4; ++dt) ot[dt] = (f32x4){0.f, 0.f, 0.f, 0.f};
#pragma unroll
  for (int dt = 0; dt < 4; ++dt) {
    const int rbv = (dt * 16 + c) * 104;
#pragma unroll
    for (int ks = 0; ks < 3; ++ks) {
      const s16x8 vh = *(const s16x8*)&sVT[rbv + ks * 32 + g * 8];
      ot[dt] = __builtin_amdgcn_mfma_f32_16x16x32_bf16(vh, ph[ks], ot[dt], 0, 0, 0);
    }
  }

  u16* op = O + ((size_t)(b * SS + qrow)) * DD + h * HDIM;
#pragma unroll
  for (int dt = 0; dt < 4; ++dt) {
    s16x4 pk;
#pragma unroll
    for (int i = 0; i < 4; ++i) pk[i] = (short)f2bf(ot[dt][i] * inv);
    *(s16x4*)&op[dt * 16 + 4 * g] = pk;
  }
}

// ---------------- legacy VALU attention (bf16 fallback path only) ----------------
__global__ __launch_bounds__(256)
void attn_win(const u16* __restrict__ Qp, const u16* __restrict__ Kp,
              const u16* __restrict__ Vp, const uint8_t* __restrict__ mk,
              u16* __restrict__ O) {
  constexpr int KR = 96;
  __shared__ float sK[KR][HDIM];
  __shared__ float sV[KR][HDIM];
  __shared__ float sM[KR];

  const int bh = blockIdx.x;
  const int b = bh >> 3, h = bh & 7;
  const int s0 = blockIdx.y * 64;
  const int tid = threadIdx.x;

  for (int c = tid; c < KR * 16; c += 256) {
    const int row = c >> 4, c4 = c & 15;
    const int gr = s0 - 16 + row;
    float kv[4], vv[4];
    if (gr >= 0 && gr < SS) {
      const size_t base = ((size_t)(b * SS + gr)) * DD + h * HDIM + c4 * 4;
      const s16x4 kk = *(const s16x4*)(Kp + base);
      const s16x4 vx = *(const s16x4*)(Vp + base);
#pragma unroll
      for (int i = 0; i < 4; ++i) { kv[i] = bf2f((u16)kk[i]); vv[i] = bf2f((u16)vx[i]); }
    } else {
#pragma unroll
      for (int i = 0; i < 4; ++i) { kv[i] = 0.f; vv[i] = 0.f; }
    }
#pragma unroll
    for (int i = 0; i < 4; ++i) {
      const int d = c4 * 4 + i;
      const int pd = (d & 15) * 4 + (d >> 4);
      sK[row][pd] = kv[i];
      sV[row][pd] = vv[i];
    }
  }
  for (int r = tid; r < KR; r += 256) {
    const int gr = s0 - 16 + r;
    sM[r] = (gr < 0 || gr >= SS || mk[b * SS + gr]) ? 1.f : 0.f;
  }
  __syncthreads();

  const int wv = tid >> 6, lane = tid & 63;
  const int g = lane >> 4, d16 = lane & 15;

  for (int rr = 0; rr < 16; rr += 4) {
    const int lr = wv * 16 + rr + g;
    const int srow = s0 + lr;
    const u16* qp = Qp + ((size_t)(b * SS + srow)) * DD + h * HDIM;
    float q0 = bf2f(qp[d16]), q1 = bf2f(qp[d16 + 16]), q2 = bf2f(qp[d16 + 32]), q3 = bf2f(qp[d16 + 48]);
    float sc[33];
#pragma unroll
    for (int o = 0; o < 33; ++o) {
      const f32x4 kk = *(const f32x4*)&sK[lr + o][d16 * 4];
      float p = q0 * kk[0] + q1 * kk[1] + q2 * kk[2] + q3 * kk[3];
      p += __shfl_xor(p, 1);
      p += __shfl_xor(p, 2);
      p += __shfl_xor(p, 4);
      p += __shfl_xor(p, 8);
      sc[o] = (sM[lr + o] != 0.f) ? -1.0e9f : p;
    }
    float mx = sc[0];
#pragma unroll
    for (int o = 1; o < 33; ++o) mx = fmaxf(mx, sc[o]);
    float sum = 0.f;
#pragma unroll
    for (int o = 0; o < 33; ++o) { const float e = __expf(sc[o] - mx); sc[o] = e; sum += e; }
    const float inv = 1.f / sum;
    f32x4 acc = (f32x4){0.f, 0.f, 0.f, 0.f};
#pragma unroll
    for (int o = 0; o < 33; ++o) {
      const f32x4 vx = *(const f32x4*)&sV[lr + o][d16 * 4];
      acc += (sc[o] * inv) * vx;
    }
    u16* op = O + ((size_t)(b * SS + srow)) * DD + h * HDIM;
    op[d16]      = f2bf(acc[0]);
    op[d16 + 16] = f2bf(acc[1]);
    op[d16 + 32] = f2bf(acc[2]);
    op[d16 + 48] = f2bf(acc[3]);
  }
}

// ---------------- launch ----------------
extern "C" void kernel_launch(void* const* d_in, const int* in_sizes, int n_in,
                              void* d_out, int out_size, void* d_ws, size_t ws_size,
                              hipStream_t stream) {
  const float* query = (const float*)d_in[0];
  const float* key   = (const float*)d_in[1];
  const float* value = (const float*)d_in[2];
  const void*  mraw  = d_in[3];
  const float* Wq = (const float*)d_in[4];
  const float* bq = (const float*)d_in[5];
  const float* Wk = (const float*)d_in[6];
  const float* bk = (const float*)d_in[7];
  const float* Wv = (const float*)d_in[8];
  const float* bv = (const float*)d_in[9];
  const float* Wo = (const float*)d_in[10];
  const float* bo = (const float*)d_in[11];

  const int M = BB * SS, N = DD, K = DD;

  char* ws = (char*)d_ws;
  size_t off = 0;
  auto carve = [&](size_t bytes) -> char* {
    char* p = ws + off;
    off = (off + bytes + 255) & ~(size_t)255;
    return p;
  };
  u16* wAll   = (u16*)carve((size_t)4 * DD * DD * sizeof(u16));
  uint8_t* mk = (uint8_t*)carve((size_t)BB * SS);
  u16* Xb     = (u16*)carve((size_t)M * DD * 2);   // bf16 A staging; later aliased as AO

  const size_t qkv_f32 = (size_t)M * DD * 4;
  const bool f32p = (off + 3 * qkv_f32 + 1024) <= ws_size;

  cvt_weights<<<(DD * DD + 255) / 256, 256, 0, stream>>>(Wq, Wk, Wv, Wo, wAll);
  mask_unpack<<<16, 256, 0, stream>>>(mraw, mk, BB * SS);

  const int n8 = M * DD / 8;
  const dim3 gc(2048);
  const dim3 gg((M / 128) * (N / 128));
  const dim3 ga(BB * HH, SS / 64);
  u16* AO = Xb;  // Xb is dead after the V GEMM consumes it; attn writes AO there

  if (f32p) {
    float* Qf = (float*)carve(qkv_f32);
    float* Kf = (float*)carve(qkv_f32);
    float* Vf = (float*)carve(qkv_f32);
    cvt_f32_bf16<<<gc, 256, 0, stream>>>(query, Xb, n8);
    gemm97<float><<<gg, 256, 0, stream>>>(Xb, wAll,               bq, Qf, M, N, K);
    cvt_f32_bf16<<<gc, 256, 0, stream>>>(key, Xb, n8);
    gemm97<float><<<gg, 256, 0, stream>>>(Xb, wAll + DD * DD,     bk, Kf, M, N, K);
    cvt_f32_bf16<<<gc, 256, 0, stream>>>(value, Xb, n8);
    gemm97<float><<<gg, 256, 0, stream>>>(Xb, wAll + 2 * DD * DD, bv, Vf, M, N, K);
    attn_mfma<<<ga, 256, 0, stream>>>(Qf, Kf, Vf, mk, AO);
  } else {
    const size_t qkv_b16 = (size_t)M * DD * 2;
    u16* Qb = (u16*)carve(qkv_b16);
    u16* Kb = (u16*)carve(qkv_b16);
    u16* Vb = (u16*)carve(qkv_b16);
    cvt_f32_bf16<<<gc, 256, 0, stream>>>(query, Xb, n8);
    gemm97<u16><<<gg, 256, 0, stream>>>(Xb, wAll,               bq, Qb, M, N, K);
    cvt_f32_bf16<<<gc, 256, 0, stream>>>(key, Xb, n8);
    gemm97<u16><<<gg, 256, 0, stream>>>(Xb, wAll + DD * DD,     bk, Kb, M, N, K);
    cvt_f32_bf16<<<gc, 256, 0, stream>>>(value, Xb, n8);
    gemm97<u16><<<gg, 256, 0, stream>>>(Xb, wAll + 2 * DD * DD, bv, Vb, M, N, K);
    attn_win<<<ga, 256, 0, stream>>>(Qb, Kb, Vb, mk, AO);
  }
  gemm97<float><<<gg, 256, 0, stream>>>(AO, wAll + 3 * DD * DD, bo, (float*)d_out, M, N, K);
}

// Round 5
// 234.094 us; speedup vs baseline: 1.9445x; 1.1024x over previous
//
#include <hip/hip_runtime.h>
#include <hip/hip_bf16.h>
#include <stdint.h>

#define BB 8
#define SS 4096
#define DD 512
#define HH 8
#define HDIM 64

typedef unsigned short u16;
typedef __attribute__((ext_vector_type(4))) float f32x4;
typedef __attribute__((ext_vector_type(4))) short s16x4;
typedef __attribute__((ext_vector_type(8))) short s16x8;
typedef __attribute__((ext_vector_type(4))) unsigned int u32x4;

__device__ __forceinline__ u16 f2bf(float f) {
  uint32_t x = __builtin_bit_cast(uint32_t, f);
  x += 0x7fffu + ((x >> 16) & 1u);
  return (u16)(x >> 16);
}
__device__ __forceinline__ float bf2f(u16 u) {
  uint32_t x = (uint32_t)u << 16;
  return __builtin_bit_cast(float, x);
}
// packed f32x2 -> bf16x2 (RNE), hw instruction; d = {hi:bf16(b), lo:bf16(a)}
__device__ __forceinline__ uint32_t cvtpk(float a, float b) {
  uint32_t d;
  asm("v_cvt_pk_bf16_f32 %0, %1, %2" : "=v"(d) : "v"(a), "v"(b));
  return d;
}

// async global->LDS, 16B/lane: LDS arg is the WAVE-UNIFORM base; HW adds lane*16.
__device__ __forceinline__ void gld_lds16(const void* g, void* l) {
  __builtin_amdgcn_global_load_lds((const __attribute__((address_space(1))) void*)g,
                                   (__attribute__((address_space(3))) void*)l, 16, 0, 0);
}

// ---------------- weight conversion: 4 x [512*512] f32 -> bf16 ----------------
__global__ void cvt_weights(const float* __restrict__ w0, const float* __restrict__ w1,
                            const float* __restrict__ w2, const float* __restrict__ w3,
                            u16* __restrict__ out) {
  int i = blockIdx.x * blockDim.x + threadIdx.x;
  const int n = DD * DD;
  if (i < n) {
    out[i]         = f2bf(w0[i]);
    out[n + i]     = f2bf(w1[i]);
    out[2 * n + i] = f2bf(w2[i]);
    out[3 * n + i] = f2bf(w3[i]);
  }
}

// ---------------- mask dtype sniff + unpack to canonical u8 ----------------
__global__ void mask_unpack(const void* __restrict__ mraw, uint8_t* __restrict__ mk, int n) {
  __shared__ int bad[3];
  __shared__ int mode;
  const int t = threadIdx.x;
  if (t < 3) bad[t] = 0;
  __syncthreads();
  const uint32_t* w = (const uint32_t*)mraw;
  const uint32_t x = w[t];
  const bool w01 = (x == 0u) || (x == 1u);
  const uint32_t ob = x | (x >> 8) | (x >> 16) | (x >> 24);
  const bool u01 = ((ob & 0xFEu) == 0u);
  if (!w01) atomicAdd(&bad[0], 1);
  if (!u01) atomicAdd(&bad[1], 1);
  __syncthreads();
  if (t == 0) mode = (bad[0] == 0) ? 0 : (bad[1] == 0 ? 1 : 2);
  __syncthreads();
  const int md = mode;
  for (int i = blockIdx.x * 256 + t; i < n; i += gridDim.x * 256) {
    uint8_t v;
    if (md == 0)      v = (uint8_t)(w[i] & 1u);
    else if (md == 1) v = ((const uint8_t*)mraw)[i] ? 1 : 0;
    else              v = (w[i] != 0u) ? 1 : 0;
    mk[i] = v;
  }
}

// ---------------- GEMM m97-structure, BK=64, XOR-swizzled LDS ----------------
// C[m][n] = sum_k A[m][k]*Bw[n][k] + bias[n].  TA=float: A staged as f32 and
// converted to bf16 in the fragment read via v_cvt_pk_bf16_f32 (RNE) — this fuses
// the old cvt pass into the GEMM. TA=u16: bf16 A (O-projection path).
// Swizzle (rule 21, both-sides): gload_lds writes linear (uniform base + lane*16),
// so the per-lane GLOBAL chunk is pre-permuted (chunk ^= row&mask) and the frag
// read XORs the same pattern -> reads are logically exact, banks fully spread
// (f32 rows: 16 slots, conflict-free; bf16 rows: 8 slots, 2-way = free).
// Grid 1-D: 4 col-siblings of one A row-panel land on the same XCD (id%8).
template <typename TA, typename TC>
__global__ __launch_bounds__(256, 2)
void gemm97(const TA* __restrict__ A, const u16* __restrict__ Bw,
            const float* __restrict__ bias, TC* __restrict__ C,
            int M, int N, int K) {
  constexpr bool AF32 = (sizeof(TA) == 4);
  constexpr int ABYTES = AF32 ? 128 * 64 * 4 : 128 * 64 * 2;
  __shared__ __align__(16) char sA[ABYTES];
  __shared__ __align__(16) u16 sB[128 * 64];

  const int tid = threadIdx.x;
  const int lane = tid & 63, wv = tid >> 6;
  const int wr = (wv >> 1) * 64, wc = (wv & 1) * 64;
  const int c = lane & 15, g = lane >> 4;
  const int lid = blockIdx.x;
  const int rb = (lid >> 5) * 8 + (lid & 7);
  const int cb = (lid >> 3) & 3;
  const int col0 = cb * 128, row0 = rb * 128;

  // staging sources (swizzled global chunk per lane)
  const int srB = tid >> 3, cBc = (tid & 7) ^ ((tid >> 3) & 7);     // 128B rows
  const u16* b_src = Bw + (size_t)(col0 + srB) * K + cBc * 8;
  const int srA = tid >> 4, cAc = (tid & 15) ^ (tid >> 4);          // 256B rows (f32)
  const TA* a_srcF = A + (size_t)(row0 + srA) * K + cAc * 4;
  const TA* a_srcH = A + (size_t)(row0 + srB) * K + cBc * 8;

  f32x4 acc[4][4];
#pragma unroll
  for (int a = 0; a < 4; ++a)
#pragma unroll
    for (int b = 0; b < 4; ++b) acc[a][b] = (f32x4){0.f, 0.f, 0.f, 0.f};

  const int nkt = K / 64;
  for (int kt = 0; kt < nkt; ++kt) {
    __syncthreads();
    const int ko = kt * 64;
    if constexpr (AF32) {
#pragma unroll
      for (int i = 0; i < 8; ++i)
        gld_lds16(a_srcF + (size_t)i * 16 * K + ko, sA + i * 4096 + wv * 1024);
    } else {
#pragma unroll
      for (int i = 0; i < 4; ++i)
        gld_lds16(a_srcH + (size_t)i * 32 * K + ko, sA + i * 4096 + wv * 1024);
    }
#pragma unroll
    for (int i = 0; i < 4; ++i)
      gld_lds16(b_src + (size_t)i * 32 * K + ko, (char*)sB + i * 4096 + wv * 1024);
    __syncthreads();   // drains vmcnt -> LDS tile complete

#pragma unroll
    for (int ks = 0; ks < 2; ++ks) {
      s16x8 af[4], bq[4];
#pragma unroll
      for (int mf = 0; mf < 4; ++mf) {
        const int row = wr + mf * 16 + c;
        if constexpr (AF32) {
          const int bc = ks * 128 + g * 32;
          const f32x4 lo4 = *(const f32x4*)(sA + row * 256 + ((bc) ^ (c << 4)));
          const f32x4 hi4 = *(const f32x4*)(sA + row * 256 + ((bc + 16) ^ (c << 4)));
          const u32x4 dd = (u32x4){cvtpk(lo4[0], lo4[1]), cvtpk(lo4[2], lo4[3]),
                                   cvtpk(hi4[0], hi4[1]), cvtpk(hi4[2], hi4[3])};
          af[mf] = __builtin_bit_cast(s16x8, dd);
        } else {
          const int bc = ks * 64 + g * 16;
          af[mf] = *(const s16x8*)(sA + row * 128 + (bc ^ ((c & 7) << 4)));
        }
      }
#pragma unroll
      for (int nf = 0; nf < 4; ++nf) {
        const int row = wc + nf * 16 + c;
        const int bc = ks * 64 + g * 16;
        bq[nf] = *(const s16x8*)((char*)sB + row * 128 + (bc ^ ((c & 7) << 4)));
      }
#pragma unroll
      for (int mf = 0; mf < 4; ++mf)
#pragma unroll
        for (int nf = 0; nf < 4; ++nf)
          acc[mf][nf] = __builtin_amdgcn_mfma_f32_16x16x32_bf16(af[mf], bq[nf], acc[mf][nf], 0, 0, 0);
    }
  }

  // epilogue: C/D layout col=lane&15, row=4*(lane>>4)+i
#pragma unroll
  for (int nf = 0; nf < 4; ++nf) {
    const int col = col0 + wc + nf * 16 + c;
    const float bv = bias[col];
#pragma unroll
    for (int mf = 0; mf < 4; ++mf) {
#pragma unroll
      for (int i = 0; i < 4; ++i) {
        const int row = row0 + wr + mf * 16 + g * 4 + i;
        const float v = acc[mf][nf][i] + bv;
        if constexpr (sizeof(TC) == 4) C[(size_t)row * N + col] = v;
        else                           C[(size_t)row * N + col] = (TC)f2bf(v);
      }
    }
  }
}

// ---------------- MFMA banded attention: LDS-staged bf16 fragments ----------------
// Q,K f32 (hi/lo split for score precision); V bf16 (produced by V-GEMM; PV uses
// V-hi only, bit-identical to before). Swapped QK^T (S^T=K*Q^T) keeps softmax
// lane-local; exp'd S^T fragments ARE the PV B-operand. Bias: off-band -2e9,
// in-band masked/OOB -1e9 (replace semantics -> all-masked row = ref's uniform 1/33;
// OOB rows have V zeroed so pads drop out of PV).
__device__ __forceinline__ void hilo8(const f32x4& a0, const f32x4& a1, s16x8& h, s16x8& l) {
#pragma unroll
  for (int j = 0; j < 4; ++j) {
    const float f = a0[j];
    const u16 hb = f2bf(f);
    h[j] = (short)hb;
    l[j] = (short)f2bf(f - bf2f(hb));
  }
#pragma unroll
  for (int j = 0; j < 4; ++j) {
    const float f = a1[j];
    const u16 hb = f2bf(f);
    h[4 + j] = (short)hb;
    l[4 + j] = (short)f2bf(f - bf2f(hb));
  }
}

__global__ __launch_bounds__(256, 4)
void attn_mfma(const float* __restrict__ Qp, const float* __restrict__ Kp,
               const u16* __restrict__ Vp, const uint8_t* __restrict__ mk,
               u16* __restrict__ O) {
  // LDS total 40384B (<40448) -> 4 blocks/CU.
  __shared__ u16 sKh[96 * 72];   // 13824B, 144B rows (16B-aligned, 2-way banks)
  __shared__ u16 sKl[96 * 68];   // 13056B
  __shared__ u16 sVT[64 * 104];  // 13312B, 208B rows (16B-aligned, 2-way banks)
  __shared__ u16 sM[96];         // 192B

  const int bh = blockIdx.x;
  const int b = bh >> 3, h = bh & 7;
  const int s0 = blockIdx.y * 64;
  const int tid = threadIdx.x;

  const int wv = tid >> 6, lane = tid & 63;
  const int c = lane & 15, g = lane >> 4;
  const int qloc = wv * 16 + c;
  const int qrow = s0 + qloc;

  // Q prefetch BEFORE staging: global loads overlap the K/V stage.
  const float* qp = Qp + ((size_t)(b * SS + qrow)) * DD + h * HDIM;
  f32x4 qa0[2], qa1[2];
#pragma unroll
  for (int ks = 0; ks < 2; ++ks) {
    qa0[ks] = *(const f32x4*)(qp + 32 * ks + 4 * g);
    qa1[ks] = *(const f32x4*)(qp + 32 * ks + 16 + 4 * g);
  }

  // ---- K staging: 96 rows x 8 granules; granule j=(ks*4+g2) <- dims {32ks+4g2+i, +16} ----
#pragma unroll
  for (int it = 0; it < 3; ++it) {
    const int item = tid + it * 256;
    const int row = item >> 3, j = item & 7;
    const int ks = j >> 2, g2 = j & 3;
    const int gr = s0 - 16 + row;
    f32x4 a0 = (f32x4){0.f, 0.f, 0.f, 0.f}, a1 = (f32x4){0.f, 0.f, 0.f, 0.f};
    if (gr >= 0 && gr < SS) {
      const float* kp = Kp + ((size_t)(b * SS + gr)) * DD + h * HDIM + ks * 32 + g2 * 4;
      a0 = *(const f32x4*)kp;
      a1 = *(const f32x4*)(kp + 16);
    }
    s16x8 hh, ll;
    hilo8(a0, a1, hh, ll);
    *(s16x8*)&sKh[row * 72 + j * 8] = hh;
    *(s16x4*)&sKl[row * 68 + j * 8]     = (s16x4){ll[0], ll[1], ll[2], ll[3]};
    *(s16x4*)&sKl[row * 68 + j * 8 + 4] = (s16x4){ll[4], ll[5], ll[6], ll[7]};
  }
  // ---- V staging (bf16 input, transposed): key k -> column pos in dim-rows ----
#pragma unroll
  for (int it = 0; it < 3; ++it) {
    const int item = tid + it * 256;
    const int k = item >> 3, dg8 = item & 7;
    const int gr = s0 - 16 + k;
    s16x8 vv = (s16x8){0, 0, 0, 0, 0, 0, 0, 0};
    if (gr >= 0 && gr < SS)
      vv = *(const s16x8*)(Vp + ((size_t)(b * SS + gr)) * DD + h * HDIM + dg8 * 8);
    const int ks = k >> 5, rem = k & 31, hf = rem >> 4, q = rem & 15;
    const int g2 = q >> 2, i2 = q & 3;
    const int pos = (ks * 4 + g2) * 8 + hf * 4 + i2;
#pragma unroll
    for (int i = 0; i < 8; ++i) sVT[(dg8 * 8 + i) * 104 + pos] = (u16)vv[i];
  }
  for (int r = tid; r < 96; r += 256) {
    const int gr = s0 - 16 + r;
    sM[r] = (gr < 0 || gr >= SS || mk[b * SS + gr]) ? 1 : 0;
  }
  __syncthreads();

  s16x8 qh[2], qlo[2];
#pragma unroll
  for (int ks = 0; ks < 2; ++ks) hilo8(qa0[ks], qa1[ks], qh[ks], qlo[ks]);

  // S^T = K·Q^T over 6 key-tiles
  f32x4 st[6];
#pragma unroll
  for (int kt = 0; kt < 6; ++kt) st[kt] = (f32x4){0.f, 0.f, 0.f, 0.f};
#pragma unroll
  for (int kt = 0; kt < 6; ++kt) {
    const int rb72 = (kt * 16 + c) * 72;
    const int rb68 = (kt * 16 + c) * 68;
#pragma unroll
    for (int ks = 0; ks < 2; ++ks) {
      const s16x8 kh = *(const s16x8*)&sKh[rb72 + ks * 32 + g * 8];
      const s16x4 l0 = *(const s16x4*)&sKl[rb68 + ks * 32 + g * 8];
      const s16x4 l1 = *(const s16x4*)&sKl[rb68 + ks * 32 + g * 8 + 4];
      const s16x8 kl = (s16x8){l0[0], l0[1], l0[2], l0[3], l1[0], l1[1], l1[2], l1[3]};
      st[kt] = __builtin_amdgcn_mfma_f32_16x16x32_bf16(kh, qh[ks], st[kt], 0, 0, 0);
      st[kt] = __builtin_amdgcn_mfma_f32_16x16x32_bf16(kh, qlo[ks], st[kt], 0, 0, 0);
      st[kt] = __builtin_amdgcn_mfma_f32_16x16x32_bf16(kl, qh[ks], st[kt], 0, 0, 0);
    }
  }

  // bias (replace) + softmax, lane-local per q-row
  float mx = -3.0e9f;
#pragma unroll
  for (int kt = 0; kt < 6; ++kt) {
#pragma unroll
    for (int i = 0; i < 4; ++i) {
      const int kl_ = kt * 16 + 4 * g + i;
      const int delta = kl_ - 16 - qloc;
      float v;
      if (delta < -16 || delta > 16) v = -2.0e9f;
      else if (sM[kl_])              v = -1.0e9f;
      else                           v = st[kt][i];
      st[kt][i] = v;
      mx = fmaxf(mx, v);
    }
  }
  mx = fmaxf(mx, __shfl_xor(mx, 16));
  mx = fmaxf(mx, __shfl_xor(mx, 32));
  float sum = 0.f;
#pragma unroll
  for (int kt = 0; kt < 6; ++kt) {
#pragma unroll
    for (int i = 0; i < 4; ++i) {
      const float e = __expf(st[kt][i] - mx);
      st[kt][i] = e;
      sum += e;
    }
  }
  sum += __shfl_xor(sum, 16);
  sum += __shfl_xor(sum, 32);
  const float inv = 1.f / sum;

  // P^T fragments (B operand of PV), hi only
  s16x8 ph[3];
#pragma unroll
  for (int ks = 0; ks < 3; ++ks) {
#pragma unroll
    for (int i = 0; i < 4; ++i) {
      ph[ks][i]     = (short)f2bf(st[2 * ks][i]);
      ph[ks][4 + i] = (short)f2bf(st[2 * ks + 1][i]);
    }
  }

  // out^T = V^T·P^T : 4 dim-tiles x 3 ksteps, A-frag = 1 b128 from sVT
  f32x4 ot[4];
#pragma unroll
  for (int dt = 0; dt < 4; ++dt) ot[dt] = (f32x4){0.f, 0.f, 0.f, 0.f};
#pragma unroll
  for (int dt = 0; dt < 4; ++dt) {
    const int rbv = (dt * 16 + c) * 104;
#pragma unroll
    for (int ks = 0; ks < 3; ++ks) {
      const s16x8 vh = *(const s16x8*)&sVT[rbv + ks * 32 + g * 8];
      ot[dt] = __builtin_amdgcn_mfma_f32_16x16x32_bf16(vh, ph[ks], ot[dt], 0, 0, 0);
    }
  }

  u16* op = O + ((size_t)(b * SS + qrow)) * DD + h * HDIM;
#pragma unroll
  for (int dt = 0; dt < 4; ++dt) {
    s16x4 pk;
#pragma unroll
    for (int i = 0; i < 4; ++i) pk[i] = (short)f2bf(ot[dt][i] * inv);
    *(s16x4*)&op[dt * 16 + 4 * g] = pk;
  }
}

// ---------------- legacy VALU attention (bf16 fallback path only) ----------------
__global__ __launch_bounds__(256)
void attn_win(const u16* __restrict__ Qp, const u16* __restrict__ Kp,
              const u16* __restrict__ Vp, const uint8_t* __restrict__ mk,
              u16* __restrict__ O) {
  constexpr int KR = 96;
  __shared__ float sK[KR][HDIM];
  __shared__ float sV[KR][HDIM];
  __shared__ float sMf[KR];

  const int bh = blockIdx.x;
  const int b = bh >> 3, h = bh & 7;
  const int s0 = blockIdx.y * 64;
  const int tid = threadIdx.x;

  for (int c = tid; c < KR * 16; c += 256) {
    const int row = c >> 4, c4 = c & 15;
    const int gr = s0 - 16 + row;
    float kv[4], vv[4];
    if (gr >= 0 && gr < SS) {
      const size_t base = ((size_t)(b * SS + gr)) * DD + h * HDIM + c4 * 4;
      const s16x4 kk = *(const s16x4*)(Kp + base);
      const s16x4 vx = *(const s16x4*)(Vp + base);
#pragma unroll
      for (int i = 0; i < 4; ++i) { kv[i] = bf2f((u16)kk[i]); vv[i] = bf2f((u16)vx[i]); }
    } else {
#pragma unroll
      for (int i = 0; i < 4; ++i) { kv[i] = 0.f; vv[i] = 0.f; }
    }
#pragma unroll
    for (int i = 0; i < 4; ++i) {
      const int d = c4 * 4 + i;
      const int pd = (d & 15) * 4 + (d >> 4);
      sK[row][pd] = kv[i];
      sV[row][pd] = vv[i];
    }
  }
  for (int r = tid; r < KR; r += 256) {
    const int gr = s0 - 16 + r;
    sMf[r] = (gr < 0 || gr >= SS || mk[b * SS + gr]) ? 1.f : 0.f;
  }
  __syncthreads();

  const int wv = tid >> 6, lane = tid & 63;
  const int g = lane >> 4, d16 = lane & 15;

  for (int rr = 0; rr < 16; rr += 4) {
    const int lr = wv * 16 + rr + g;
    const int srow = s0 + lr;
    const u16* qp = Qp + ((size_t)(b * SS + srow)) * DD + h * HDIM;
    float q0 = bf2f(qp[d16]), q1 = bf2f(qp[d16 + 16]), q2 = bf2f(qp[d16 + 32]), q3 = bf2f(qp[d16 + 48]);
    float sc[33];
#pragma unroll
    for (int o = 0; o < 33; ++o) {
      const f32x4 kk = *(const f32x4*)&sK[lr + o][d16 * 4];
      float p = q0 * kk[0] + q1 * kk[1] + q2 * kk[2] + q3 * kk[3];
      p += __shfl_xor(p, 1);
      p += __shfl_xor(p, 2);
      p += __shfl_xor(p, 4);
      p += __shfl_xor(p, 8);
      sc[o] = (sMf[lr + o] != 0.f) ? -1.0e9f : p;
    }
    float mx = sc[0];
#pragma unroll
    for (int o = 1; o < 33; ++o) mx = fmaxf(mx, sc[o]);
    float sum = 0.f;
#pragma unroll
    for (int o = 0; o < 33; ++o) { const float e = __expf(sc[o] - mx); sc[o] = e; sum += e; }
    const float inv = 1.f / sum;
    f32x4 acc = (f32x4){0.f, 0.f, 0.f, 0.f};
#pragma unroll
    for (int o = 0; o < 33; ++o) {
      const f32x4 vx = *(const f32x4*)&sV[lr + o][d16 * 4];
      acc += (sc[o] * inv) * vx;
    }
    u16* op = O + ((size_t)(b * SS + srow)) * DD + h * HDIM;
    op[d16]      = f2bf(acc[0]);
    op[d16 + 16] = f2bf(acc[1]);
    op[d16 + 32] = f2bf(acc[2]);
    op[d16 + 48] = f2bf(acc[3]);
  }
}

// ---------------- launch ----------------
extern "C" void kernel_launch(void* const* d_in, const int* in_sizes, int n_in,
                              void* d_out, int out_size, void* d_ws, size_t ws_size,
                              hipStream_t stream) {
  const float* query = (const float*)d_in[0];
  const float* key   = (const float*)d_in[1];
  const float* value = (const float*)d_in[2];
  const void*  mraw  = d_in[3];
  const float* Wq = (const float*)d_in[4];
  const float* bq = (const float*)d_in[5];
  const float* Wk = (const float*)d_in[6];
  const float* bk = (const float*)d_in[7];
  const float* Wv = (const float*)d_in[8];
  const float* bv = (const float*)d_in[9];
  const float* Wo = (const float*)d_in[10];
  const float* bo = (const float*)d_in[11];

  const int M = BB * SS, N = DD, K = DD;

  char* ws = (char*)d_ws;
  size_t off = 0;
  auto carve = [&](size_t bytes) -> char* {
    char* p = ws + off;
    off = (off + bytes + 255) & ~(size_t)255;
    return p;
  };
  u16* wAll   = (u16*)carve((size_t)4 * DD * DD * sizeof(u16));
  uint8_t* mk = (uint8_t*)carve((size_t)BB * SS);

  const size_t qk_f32 = (size_t)M * DD * 4;
  const size_t v_b16  = (size_t)M * DD * 2;
  const bool f32p = (off + 2 * qk_f32 + 2 * v_b16 + 1024) <= ws_size;

  cvt_weights<<<(DD * DD + 255) / 256, 256, 0, stream>>>(Wq, Wk, Wv, Wo, wAll);
  mask_unpack<<<16, 256, 0, stream>>>(mraw, mk, BB * SS);

  const dim3 gg((M / 128) * (N / 128));   // 1024, XCD-grouped in-kernel
  const dim3 ga(BB * HH, SS / 64);

  if (f32p) {
    float* Qf = (float*)carve(qk_f32);
    float* Kf = (float*)carve(qk_f32);
    u16*   Vb = (u16*)carve(v_b16);
    u16*   AO = (u16*)carve(v_b16);
    gemm97<float, float><<<gg, 256, 0, stream>>>(query, wAll,               bq, Qf, M, N, K);
    gemm97<float, float><<<gg, 256, 0, stream>>>(key,   wAll + DD * DD,     bk, Kf, M, N, K);
    gemm97<float, u16><<<gg, 256, 0, stream>>>(value, wAll + 2 * DD * DD, bv, Vb, M, N, K);
    attn_mfma<<<ga, 256, 0, stream>>>(Qf, Kf, Vb, mk, AO);
    gemm97<u16, float><<<gg, 256, 0, stream>>>(AO, wAll + 3 * DD * DD, bo, (float*)d_out, M, N, K);
  } else {
    u16* Qb = (u16*)carve(v_b16);
    u16* Kb = (u16*)carve(v_b16);
    u16* Vb = (u16*)carve(v_b16);
    u16* AO = (u16*)carve(v_b16);
    gemm97<float, u16><<<gg, 256, 0, stream>>>(query, wAll,               bq, Qb, M, N, K);
    gemm97<float, u16><<<gg, 256, 0, stream>>>(key,   wAll + DD * DD,     bk, Kb, M, N, K);
    gemm97<float, u16><<<gg, 256, 0, stream>>>(value, wAll + 2 * DD * DD, bv, Vb, M, N, K);
    attn_win<<<ga, 256, 0, stream>>>(Qb, Kb, Vb, mk, AO);
    gemm97<u16, float><<<gg, 256, 0, stream>>>(AO, wAll + 3 * DD * DD, bo, (float*)d_out, M, N, K);
  }
}

// Round 6
// 228.482 us; speedup vs baseline: 1.9922x; 1.0246x over previous
//
#include <hip/hip_runtime.h>
#include <hip/hip_bf16.h>
#include <stdint.h>

#define BB 8
#define SS 4096
#define DD 512
#define HH 8
#define HDIM 64

typedef unsigned short u16;
typedef __attribute__((ext_vector_type(4))) float f32x4;
typedef __attribute__((ext_vector_type(4))) short s16x4;
typedef __attribute__((ext_vector_type(8))) short s16x8;
typedef __attribute__((ext_vector_type(4))) unsigned int u32x4;

__device__ __forceinline__ u16 f2bf(float f) {
  uint32_t x = __builtin_bit_cast(uint32_t, f);
  x += 0x7fffu + ((x >> 16) & 1u);
  return (u16)(x >> 16);
}
__device__ __forceinline__ float bf2f(u16 u) {
  uint32_t x = (uint32_t)u << 16;
  return __builtin_bit_cast(float, x);
}
// packed f32x2 -> bf16x2 (RNE), hw instruction; d = {lo:bf16(a), hi:bf16(b)}
__device__ __forceinline__ uint32_t cvtpk(float a, float b) {
  uint32_t d;
  asm("v_cvt_pk_bf16_f32 %0, %1, %2" : "=v"(d) : "v"(a), "v"(b));
  return d;
}

// async global->LDS, 16B/lane: LDS arg is the WAVE-UNIFORM base; HW adds lane*16.
__device__ __forceinline__ void gld_lds16(const void* g, void* l) {
  __builtin_amdgcn_global_load_lds((const __attribute__((address_space(1))) void*)g,
                                   (__attribute__((address_space(3))) void*)l, 16, 0, 0);
}

// ---------------- weight conversion: 4 x [512*512] f32 -> bf16 ----------------
__global__ void cvt_weights(const float* __restrict__ w0, const float* __restrict__ w1,
                            const float* __restrict__ w2, const float* __restrict__ w3,
                            u16* __restrict__ out) {
  int i = blockIdx.x * blockDim.x + threadIdx.x;
  const int n = DD * DD;
  if (i < n) {
    out[i]         = f2bf(w0[i]);
    out[n + i]     = f2bf(w1[i]);
    out[2 * n + i] = f2bf(w2[i]);
    out[3 * n + i] = f2bf(w3[i]);
  }
}

// ---------------- mask dtype sniff + unpack to canonical u8 ----------------
__global__ void mask_unpack(const void* __restrict__ mraw, uint8_t* __restrict__ mk, int n) {
  __shared__ int bad[3];
  __shared__ int mode;
  const int t = threadIdx.x;
  if (t < 3) bad[t] = 0;
  __syncthreads();
  const uint32_t* w = (const uint32_t*)mraw;
  const uint32_t x = w[t];
  const bool w01 = (x == 0u) || (x == 1u);
  const uint32_t ob = x | (x >> 8) | (x >> 16) | (x >> 24);
  const bool u01 = ((ob & 0xFEu) == 0u);
  if (!w01) atomicAdd(&bad[0], 1);
  if (!u01) atomicAdd(&bad[1], 1);
  __syncthreads();
  if (t == 0) mode = (bad[0] == 0) ? 0 : (bad[1] == 0 ? 1 : 2);
  __syncthreads();
  const int md = mode;
  for (int i = blockIdx.x * 256 + t; i < n; i += gridDim.x * 256) {
    uint8_t v;
    if (md == 0)      v = (uint8_t)(w[i] & 1u);
    else if (md == 1) v = ((const uint8_t*)mraw)[i] ? 1 : 0;
    else              v = (w[i] != 0u) ? 1 : 0;
    mk[i] = v;
  }
}

// ---------------- GEMM m97-structure, BK=64, XOR-swizzled LDS ----------------
// (unchanged from round 5 — see comments there)
template <typename TA, typename TC>
__global__ __launch_bounds__(256, 2)
void gemm97(const TA* __restrict__ A, const u16* __restrict__ Bw,
            const float* __restrict__ bias, TC* __restrict__ C,
            int M, int N, int K) {
  constexpr bool AF32 = (sizeof(TA) == 4);
  constexpr int ABYTES = AF32 ? 128 * 64 * 4 : 128 * 64 * 2;
  __shared__ __align__(16) char sA[ABYTES];
  __shared__ __align__(16) u16 sB[128 * 64];

  const int tid = threadIdx.x;
  const int lane = tid & 63, wv = tid >> 6;
  const int wr = (wv >> 1) * 64, wc = (wv & 1) * 64;
  const int c = lane & 15, g = lane >> 4;
  const int lid = blockIdx.x;
  const int rb = (lid >> 5) * 8 + (lid & 7);
  const int cb = (lid >> 3) & 3;
  const int col0 = cb * 128, row0 = rb * 128;

  const int srB = tid >> 3, cBc = (tid & 7) ^ ((tid >> 3) & 7);
  const u16* b_src = Bw + (size_t)(col0 + srB) * K + cBc * 8;
  const int srA = tid >> 4, cAc = (tid & 15) ^ (tid >> 4);
  const TA* a_srcF = A + (size_t)(row0 + srA) * K + cAc * 4;
  const TA* a_srcH = A + (size_t)(row0 + srB) * K + cBc * 8;

  f32x4 acc[4][4];
#pragma unroll
  for (int a = 0; a < 4; ++a)
#pragma unroll
    for (int b = 0; b < 4; ++b) acc[a][b] = (f32x4){0.f, 0.f, 0.f, 0.f};

  const int nkt = K / 64;
  for (int kt = 0; kt < nkt; ++kt) {
    __syncthreads();
    const int ko = kt * 64;
    if constexpr (AF32) {
#pragma unroll
      for (int i = 0; i < 8; ++i)
        gld_lds16(a_srcF + (size_t)i * 16 * K + ko, sA + i * 4096 + wv * 1024);
    } else {
#pragma unroll
      for (int i = 0; i < 4; ++i)
        gld_lds16(a_srcH + (size_t)i * 32 * K + ko, sA + i * 4096 + wv * 1024);
    }
#pragma unroll
    for (int i = 0; i < 4; ++i)
      gld_lds16(b_src + (size_t)i * 32 * K + ko, (char*)sB + i * 4096 + wv * 1024);
    __syncthreads();

#pragma unroll
    for (int ks = 0; ks < 2; ++ks) {
      s16x8 af[4], bq[4];
#pragma unroll
      for (int mf = 0; mf < 4; ++mf) {
        const int row = wr + mf * 16 + c;
        if constexpr (AF32) {
          const int bc = ks * 128 + g * 32;
          const f32x4 lo4 = *(const f32x4*)(sA + row * 256 + ((bc) ^ (c << 4)));
          const f32x4 hi4 = *(const f32x4*)(sA + row * 256 + ((bc + 16) ^ (c << 4)));
          const u32x4 dd = (u32x4){cvtpk(lo4[0], lo4[1]), cvtpk(lo4[2], lo4[3]),
                                   cvtpk(hi4[0], hi4[1]), cvtpk(hi4[2], hi4[3])};
          af[mf] = __builtin_bit_cast(s16x8, dd);
        } else {
          const int bc = ks * 64 + g * 16;
          af[mf] = *(const s16x8*)(sA + row * 128 + (bc ^ ((c & 7) << 4)));
        }
      }
#pragma unroll
      for (int nf = 0; nf < 4; ++nf) {
        const int row = wc + nf * 16 + c;
        const int bc = ks * 64 + g * 16;
        bq[nf] = *(const s16x8*)((char*)sB + row * 128 + (bc ^ ((c & 7) << 4)));
      }
#pragma unroll
      for (int mf = 0; mf < 4; ++mf)
#pragma unroll
        for (int nf = 0; nf < 4; ++nf)
          acc[mf][nf] = __builtin_amdgcn_mfma_f32_16x16x32_bf16(af[mf], bq[nf], acc[mf][nf], 0, 0, 0);
    }
  }

#pragma unroll
  for (int nf = 0; nf < 4; ++nf) {
    const int col = col0 + wc + nf * 16 + c;
    const float bv = bias[col];
#pragma unroll
    for (int mf = 0; mf < 4; ++mf) {
#pragma unroll
      for (int i = 0; i < 4; ++i) {
        const int row = row0 + wr + mf * 16 + g * 4 + i;
        const float v = acc[mf][nf][i] + bv;
        if constexpr (sizeof(TC) == 4) C[(size_t)row * N + col] = v;
        else                           C[(size_t)row * N + col] = (TC)f2bf(v);
      }
    }
  }
}

// ---------------- MFMA banded attention v5: multi-chunk + T14 async-STAGE split ----
// Each block owns CH=4 consecutive 64-row chunks. Per iteration: issue next chunk's
// K/V/Q/mask global loads into REGS (in flight during compute), compute current chunk
// from LDS, barrier, write regs->LDS, barrier. Prologue HBM latency paid once per 4
// chunks; per-chunk math identical to v4 (bit-identical output).
__device__ __forceinline__ void hilo8(const f32x4& a0, const f32x4& a1, s16x8& h, s16x8& l) {
#pragma unroll
  for (int j = 0; j < 4; ++j) {
    const float f = a0[j];
    const u16 hb = f2bf(f);
    h[j] = (short)hb;
    l[j] = (short)f2bf(f - bf2f(hb));
  }
#pragma unroll
  for (int j = 0; j < 4; ++j) {
    const float f = a1[j];
    const u16 hb = f2bf(f);
    h[4 + j] = (short)hb;
    l[4 + j] = (short)f2bf(f - bf2f(hb));
  }
}

#define ACH 4

__global__ __launch_bounds__(256, 4)
void attn_mfma(const float* __restrict__ Qp, const float* __restrict__ Kp,
               const u16* __restrict__ Vp, const uint8_t* __restrict__ mk,
               u16* __restrict__ O) {
  __shared__ u16 sKh[96 * 72];
  __shared__ u16 sKl[96 * 68];
  __shared__ u16 sVT[64 * 104];
  __shared__ u16 sM[96];

  const int bh = blockIdx.x;
  const int b = bh >> 3, h = bh & 7;
  const int base0 = blockIdx.y * (64 * ACH);
  const int tid = threadIdx.x;

  const int wv = tid >> 6, lane = tid & 63;
  const int c = lane & 15, g = lane >> 4;
  const int qloc = wv * 16 + c;

  // K-staging geometry (per thread, 3 items)
  const int krow0 = tid >> 3, kj = tid & 7;
  const int kks = kj >> 2, kg2 = kj & 3;
  // V-staging geometry (per thread, 3 items)
  const int vk0 = tid >> 3, vdg8 = tid & 7;

  // prefetch registers
  f32x4 kA0[3], kA1[3];
  s16x8 vR[3];
  u16 mR = 1;
  f32x4 qn0[2], qn1[2];

  auto issue_loads = [&](int cs) {
#pragma unroll
    for (int it = 0; it < 3; ++it) {
      const int row = krow0 + it * 32;
      const int gr = cs - 16 + row;
      if (gr >= 0 && gr < SS) {
        const float* kp = Kp + ((size_t)(b * SS + gr)) * DD + h * HDIM + kks * 32 + kg2 * 4;
        kA0[it] = *(const f32x4*)kp;
        kA1[it] = *(const f32x4*)(kp + 16);
      } else {
        kA0[it] = (f32x4){0.f, 0.f, 0.f, 0.f};
        kA1[it] = (f32x4){0.f, 0.f, 0.f, 0.f};
      }
    }
#pragma unroll
    for (int it = 0; it < 3; ++it) {
      const int k = vk0 + it * 32;
      const int gr = cs - 16 + k;
      if (gr >= 0 && gr < SS)
        vR[it] = *(const s16x8*)(Vp + ((size_t)(b * SS + gr)) * DD + h * HDIM + vdg8 * 8);
      else
        vR[it] = (s16x8){0, 0, 0, 0, 0, 0, 0, 0};
    }
    if (tid < 96) {
      const int gr = cs - 16 + tid;
      mR = (gr < 0 || gr >= SS || mk[b * SS + gr]) ? 1 : 0;
    }
    const float* qp = Qp + ((size_t)(b * SS + cs + qloc)) * DD + h * HDIM;
#pragma unroll
    for (int ks = 0; ks < 2; ++ks) {
      qn0[ks] = *(const f32x4*)(qp + 32 * ks + 4 * g);
      qn1[ks] = *(const f32x4*)(qp + 32 * ks + 16 + 4 * g);
    }
  };

  auto write_stage = [&]() {
#pragma unroll
    for (int it = 0; it < 3; ++it) {
      const int row = krow0 + it * 32;
      s16x8 hh, ll;
      hilo8(kA0[it], kA1[it], hh, ll);
      *(s16x8*)&sKh[row * 72 + kj * 8] = hh;
      *(s16x4*)&sKl[row * 68 + kj * 8]     = (s16x4){ll[0], ll[1], ll[2], ll[3]};
      *(s16x4*)&sKl[row * 68 + kj * 8 + 4] = (s16x4){ll[4], ll[5], ll[6], ll[7]};
    }
#pragma unroll
    for (int it = 0; it < 3; ++it) {
      const int k = vk0 + it * 32;
      const int ks = k >> 5, rem = k & 31, hf = rem >> 4, q = rem & 15;
      const int g2 = q >> 2, i2 = q & 3;
      const int pos = (ks * 4 + g2) * 8 + hf * 4 + i2;
#pragma unroll
      for (int i = 0; i < 8; ++i) sVT[(vdg8 * 8 + i) * 104 + pos] = (u16)vR[it][i];
    }
    if (tid < 96) sM[tid] = mR;
  };

  // prologue: stage chunk 0
  issue_loads(base0);
  write_stage();
  __syncthreads();

  for (int t = 0; t < ACH; ++t) {
    const int s0 = base0 + t * 64;
    const int qrow = s0 + qloc;

    // consume prefetched Q (before regs are overwritten by the next issue)
    s16x8 qh[2], qlo[2];
#pragma unroll
    for (int ks = 0; ks < 2; ++ks) hilo8(qn0[ks], qn1[ks], qh[ks], qlo[ks]);

    if (t + 1 < ACH) issue_loads(base0 + (t + 1) * 64);

    // S^T = K·Q^T over 6 key-tiles
    f32x4 st[6];
#pragma unroll
    for (int kt = 0; kt < 6; ++kt) st[kt] = (f32x4){0.f, 0.f, 0.f, 0.f};
#pragma unroll
    for (int kt = 0; kt < 6; ++kt) {
      const int rb72 = (kt * 16 + c) * 72;
      const int rb68 = (kt * 16 + c) * 68;
#pragma unroll
      for (int ks = 0; ks < 2; ++ks) {
        const s16x8 kh = *(const s16x8*)&sKh[rb72 + ks * 32 + g * 8];
        const s16x4 l0 = *(const s16x4*)&sKl[rb68 + ks * 32 + g * 8];
        const s16x4 l1 = *(const s16x4*)&sKl[rb68 + ks * 32 + g * 8 + 4];
        const s16x8 kl = (s16x8){l0[0], l0[1], l0[2], l0[3], l1[0], l1[1], l1[2], l1[3]};
        st[kt] = __builtin_amdgcn_mfma_f32_16x16x32_bf16(kh, qh[ks], st[kt], 0, 0, 0);
        st[kt] = __builtin_amdgcn_mfma_f32_16x16x32_bf16(kh, qlo[ks], st[kt], 0, 0, 0);
        st[kt] = __builtin_amdgcn_mfma_f32_16x16x32_bf16(kl, qh[ks], st[kt], 0, 0, 0);
      }
    }

    // bias (replace) + softmax, lane-local per q-row
    float mx = -3.0e9f;
#pragma unroll
    for (int kt = 0; kt < 6; ++kt) {
#pragma unroll
      for (int i = 0; i < 4; ++i) {
        const int kl_ = kt * 16 + 4 * g + i;
        const int delta = kl_ - 16 - qloc;
        float v;
        if (delta < -16 || delta > 16) v = -2.0e9f;
        else if (sM[kl_])              v = -1.0e9f;
        else                           v = st[kt][i];
        st[kt][i] = v;
        mx = fmaxf(mx, v);
      }
    }
    mx = fmaxf(mx, __shfl_xor(mx, 16));
    mx = fmaxf(mx, __shfl_xor(mx, 32));
    float sum = 0.f;
#pragma unroll
    for (int kt = 0; kt < 6; ++kt) {
#pragma unroll
      for (int i = 0; i < 4; ++i) {
        const float e = __expf(st[kt][i] - mx);
        st[kt][i] = e;
        sum += e;
      }
    }
    sum += __shfl_xor(sum, 16);
    sum += __shfl_xor(sum, 32);
    const float inv = 1.f / sum;

    // P^T fragments (B operand of PV), hi only
    s16x8 ph[3];
#pragma unroll
    for (int ks = 0; ks < 3; ++ks) {
#pragma unroll
      for (int i = 0; i < 4; ++i) {
        ph[ks][i]     = (short)f2bf(st[2 * ks][i]);
        ph[ks][4 + i] = (short)f2bf(st[2 * ks + 1][i]);
      }
    }

    // out^T = V^T·P^T
    f32x4 ot[4];
#pragma unroll
    for (int dt = 0; dt < 4; ++dt) ot[dt] = (f32x4){0.f, 0.f, 0.f, 0.f};
#pragma unroll
    for (int dt = 0; dt < 4; ++dt) {
      const int rbv = (dt * 16 + c) * 104;
#pragma unroll
      for (int ks = 0; ks < 3; ++ks) {
        const s16x8 vh = *(const s16x8*)&sVT[rbv + ks * 32 + g * 8];
        ot[dt] = __builtin_amdgcn_mfma_f32_16x16x32_bf16(vh, ph[ks], ot[dt], 0, 0, 0);
      }
    }

    u16* op = O + ((size_t)(b * SS + qrow)) * DD + h * HDIM;
#pragma unroll
    for (int dt = 0; dt < 4; ++dt) {
      s16x4 pk;
#pragma unroll
      for (int i = 0; i < 4; ++i) pk[i] = (short)f2bf(ot[dt][i] * inv);
      *(s16x4*)&op[dt * 16 + 4 * g] = pk;
    }

    __syncthreads();               // all waves done reading LDS of chunk t
    if (t + 1 < ACH) {
      write_stage();               // regs (already landed during compute) -> LDS
      __syncthreads();
    }
  }
}

// ---------------- legacy VALU attention (bf16 fallback path only) ----------------
__global__ __launch_bounds__(256)
void attn_win(const u16* __restrict__ Qp, const u16* __restrict__ Kp,
              const u16* __restrict__ Vp, const uint8_t* __restrict__ mk,
              u16* __restrict__ O) {
  constexpr int KR = 96;
  __shared__ float sK[KR][HDIM];
  __shared__ float sV[KR][HDIM];
  __shared__ float sMf[KR];

  const int bh = blockIdx.x;
  const int b = bh >> 3, h = bh & 7;
  const int s0 = blockIdx.y * 64;
  const int tid = threadIdx.x;

  for (int c = tid; c < KR * 16; c += 256) {
    const int row = c >> 4, c4 = c & 15;
    const int gr = s0 - 16 + row;
    float kv[4], vv[4];
    if (gr >= 0 && gr < SS) {
      const size_t base = ((size_t)(b * SS + gr)) * DD + h * HDIM + c4 * 4;
      const s16x4 kk = *(const s16x4*)(Kp + base);
      const s16x4 vx = *(const s16x4*)(Vp + base);
#pragma unroll
      for (int i = 0; i < 4; ++i) { kv[i] = bf2f((u16)kk[i]); vv[i] = bf2f((u16)vx[i]); }
    } else {
#pragma unroll
      for (int i = 0; i < 4; ++i) { kv[i] = 0.f; vv[i] = 0.f; }
    }
#pragma unroll
    for (int i = 0; i < 4; ++i) {
      const int d = c4 * 4 + i;
      const int pd = (d & 15) * 4 + (d >> 4);
      sK[row][pd] = kv[i];
      sV[row][pd] = vv[i];
    }
  }
  for (int r = tid; r < KR; r += 256) {
    const int gr = s0 - 16 + r;
    sMf[r] = (gr < 0 || gr >= SS || mk[b * SS + gr]) ? 1.f : 0.f;
  }
  __syncthreads();

  const int wv = tid >> 6, lane = tid & 63;
  const int g = lane >> 4, d16 = lane & 15;

  for (int rr = 0; rr < 16; rr += 4) {
    const int lr = wv * 16 + rr + g;
    const int srow = s0 + lr;
    const u16* qp = Qp + ((size_t)(b * SS + srow)) * DD + h * HDIM;
    float q0 = bf2f(qp[d16]), q1 = bf2f(qp[d16 + 16]), q2 = bf2f(qp[d16 + 32]), q3 = bf2f(qp[d16 + 48]);
    float sc[33];
#pragma unroll
    for (int o = 0; o < 33; ++o) {
      const f32x4 kk = *(const f32x4*)&sK[lr + o][d16 * 4];
      float p = q0 * kk[0] + q1 * kk[1] + q2 * kk[2] + q3 * kk[3];
      p += __shfl_xor(p, 1);
      p += __shfl_xor(p, 2);
      p += __shfl_xor(p, 4);
      p += __shfl_xor(p, 8);
      sc[o] = (sMf[lr + o] != 0.f) ? -1.0e9f : p;
    }
    float mx = sc[0];
#pragma unroll
    for (int o = 1; o < 33; ++o) mx = fmaxf(mx, sc[o]);
    float sum = 0.f;
#pragma unroll
    for (int o = 0; o < 33; ++o) { const float e = __expf(sc[o] - mx); sc[o] = e; sum += e; }
    const float inv = 1.f / sum;
    f32x4 acc = (f32x4){0.f, 0.f, 0.f, 0.f};
#pragma unroll
    for (int o = 0; o < 33; ++o) {
      const f32x4 vx = *(const f32x4*)&sV[lr + o][d16 * 4];
      acc += (sc[o] * inv) * vx;
    }
    u16* op = O + ((size_t)(b * SS + srow)) * DD + h * HDIM;
    op[d16]      = f2bf(acc[0]);
    op[d16 + 16] = f2bf(acc[1]);
    op[d16 + 32] = f2bf(acc[2]);
    op[d16 + 48] = f2bf(acc[3]);
  }
}

// ---------------- launch ----------------
extern "C" void kernel_launch(void* const* d_in, const int* in_sizes, int n_in,
                              void* d_out, int out_size, void* d_ws, size_t ws_size,
                              hipStream_t stream) {
  const float* query = (const float*)d_in[0];
  const float* key   = (const float*)d_in[1];
  const float* value = (const float*)d_in[2];
  const void*  mraw  = d_in[3];
  const float* Wq = (const float*)d_in[4];
  const float* bq = (const float*)d_in[5];
  const float* Wk = (const float*)d_in[6];
  const float* bk = (const float*)d_in[7];
  const float* Wv = (const float*)d_in[8];
  const float* bv = (const float*)d_in[9];
  const float* Wo = (const float*)d_in[10];
  const float* bo = (const float*)d_in[11];

  const int M = BB * SS, N = DD, K = DD;

  char* ws = (char*)d_ws;
  size_t off = 0;
  auto carve = [&](size_t bytes) -> char* {
    char* p = ws + off;
    off = (off + bytes + 255) & ~(size_t)255;
    return p;
  };
  u16* wAll   = (u16*)carve((size_t)4 * DD * DD * sizeof(u16));
  uint8_t* mk = (uint8_t*)carve((size_t)BB * SS);

  const size_t qk_f32 = (size_t)M * DD * 4;
  const size_t v_b16  = (size_t)M * DD * 2;
  const bool f32p = (off + 2 * qk_f32 + 2 * v_b16 + 1024) <= ws_size;

  cvt_weights<<<(DD * DD + 255) / 256, 256, 0, stream>>>(Wq, Wk, Wv, Wo, wAll);
  mask_unpack<<<16, 256, 0, stream>>>(mraw, mk, BB * SS);

  const dim3 gg((M / 128) * (N / 128));   // 1024, XCD-grouped in-kernel
  const dim3 ga(BB * HH, SS / (64 * ACH));

  if (f32p) {
    float* Qf = (float*)carve(qk_f32);
    float* Kf = (float*)carve(qk_f32);
    u16*   Vb = (u16*)carve(v_b16);
    u16*   AO = (u16*)carve(v_b16);
    gemm97<float, float><<<gg, 256, 0, stream>>>(query, wAll,               bq, Qf, M, N, K);
    gemm97<float, float><<<gg, 256, 0, stream>>>(key,   wAll + DD * DD,     bk, Kf, M, N, K);
    gemm97<float, u16><<<gg, 256, 0, stream>>>(value, wAll + 2 * DD * DD, bv, Vb, M, N, K);
    attn_mfma<<<ga, 256, 0, stream>>>(Qf, Kf, Vb, mk, AO);
    gemm97<u16, float><<<gg, 256, 0, stream>>>(AO, wAll + 3 * DD * DD, bo, (float*)d_out, M, N, K);
  } else {
    const dim3 ga1(BB * HH, SS / 64);
    u16* Qb = (u16*)carve(v_b16);
    u16* Kb = (u16*)carve(v_b16);
    u16* Vb = (u16*)carve(v_b16);
    u16* AO = (u16*)carve(v_b16);
    gemm97<float, u16><<<gg, 256, 0, stream>>>(query, wAll,               bq, Qb, M, N, K);
    gemm97<float, u16><<<gg, 256, 0, stream>>>(key,   wAll + DD * DD,     bk, Kb, M, N, K);
    gemm97<float, u16><<<gg, 256, 0, stream>>>(value, wAll + 2 * DD * DD, bv, Vb, M, N, K);
    attn_win<<<ga1, 256, 0, stream>>>(Qb, Kb, Vb, mk, AO);
    gemm97<u16, float><<<gg, 256, 0, stream>>>(AO, wAll + 3 * DD * DD, bo, (float*)d_out, M, N, K);
  }
}